// Round 5
// baseline (234.414 us; speedup 1.0000x reference)
//
#include <hip/hip_runtime.h>

// Problem constants (fixed by setup_inputs)
#define BATCH 2
#define NPTS  2048      // N (source points, x1/p1)
#define MPTS  8192      // M (query points, x2/p2)
#define CIN1  512       // Cin for up_mlp
#define CIN2  256       // Cin for lateral_mlp
#define COUT  256
#define ROWS1 (BATCH*NPTS)   // 4096
#define ROWS2 (BATCH*MPTS)   // 16384
#define BN_EPS 1e-5f
#define NN_EPS 1e-8f

// three_nn split-N decomposition
#define NCHUNK 16
#define CHUNK  (NPTS / NCHUNK)   // 128 points per chunk

typedef __attribute__((ext_vector_type(8))) short  bf16x8;  // 8 bf16 = 4 VGPRs
typedef __attribute__((ext_vector_type(4))) float  f32x4;   // MFMA acc

__device__ __forceinline__ unsigned short bf16_rne(float x) {
    unsigned u = __float_as_uint(x);
    u += 0x7FFFu + ((u >> 16) & 1u);
    return (unsigned short)(u >> 16);
}
__device__ __forceinline__ float bf16_f32(unsigned short h) {
    return __uint_as_float(((unsigned)h) << 16);
}
__device__ __forceinline__ void split2(float x, unsigned short& h, unsigned short& l) {
    h = bf16_rne(x);
    l = bf16_rne(x - bf16_f32(h));
}

// ---------------------------------------------------------------------------
// Split-bf16 MFMA GEMM (NT): C[row][o] = sum_k A[row][k]*W[o][k], C ld = COUT.
// f32 = hi + lo; C = Ah*Bh + Al*Bh + Ah*Bl (3 MFMA passes), 16x16x32 bf16.
// 64x64 tile, 256 threads = 4 waves (2x2), wave tile 32x32.
// Register prefetch: iter k+1's global loads issue after the stage barrier,
// hiding HBM latency under frag reads + MFMA (T14 async-stage split).
// Epilogue: acc -> LDS transpose -> float4 coalesced C stores (kills the
// partial-line write RMW seen in r3: WRITE_SIZE was 4x C bytes).
// KSPLIT>1: blockIdx.z = K-chunk, accumulate via atomicAdd (C pre-zeroed).
// FUSE_STATS: per-channel sum/sumsq from the transposed tile -> atomicAdd.
// ---------------------------------------------------------------------------
template<int K, int KSPLIT, bool FUSE_STATS>
__global__ __launch_bounds__(256)
void gemm_mfma64(const float* __restrict__ A, const float* __restrict__ W,
                 float* __restrict__ C, float* __restrict__ stats) {
    constexpr int BK = 32;          // f32 k per stage
    constexpr int LDK = 40;         // padded row length (bf16)
    constexpr int KCH = K / KSPLIT; // K-chunk per block
    __shared__ union {
        struct { unsigned short Ah[64][LDK], Al[64][LDK], Bh[64][LDK], Bl[64][LDK]; } s;
        struct { float Ct[64][68]; float red[64][8]; } e;
    } U;

    const int tid = threadIdx.x;
    const int m0 = blockIdx.y * 64;
    const int o0 = blockIdx.x * 64;
    const int kbase = blockIdx.z * KCH;
    const int lane = tid & 63, wid = tid >> 6;
    const int wy = wid >> 1, wx = wid & 1;
    const int lr = lane & 15, lg = lane >> 4;
    const int sr = tid >> 3;              // 0..31 staging row
    const int squad = (tid & 7) * 4;      // staging k offset (float4)

    f32x4 acc[2][2];
    #pragma unroll
    for (int i = 0; i < 2; ++i)
        #pragma unroll
        for (int j = 0; j < 2; ++j)
            acc[i][j] = (f32x4){0.f, 0.f, 0.f, 0.f};

    const float* Abase = A + (size_t)m0 * K + kbase + squad;
    const float* Wbase = W + (size_t)o0 * K + kbase + squad;

    // preload iteration 0
    float4 va0 = *(const float4*)(Abase + (size_t)sr * K);
    float4 va1 = *(const float4*)(Abase + (size_t)(sr + 32) * K);
    float4 vb0 = *(const float4*)(Wbase + (size_t)sr * K);
    float4 vb1 = *(const float4*)(Wbase + (size_t)(sr + 32) * K);

    for (int k0 = 0; k0 < KCH; k0 += BK) {
        __syncthreads();   // previous iteration's frag reads done
        {
            ushort4 h, l;
            split2(va0.x, h.x, l.x); split2(va0.y, h.y, l.y);
            split2(va0.z, h.z, l.z); split2(va0.w, h.w, l.w);
            *(ushort4*)&U.s.Ah[sr][squad] = h;
            *(ushort4*)&U.s.Al[sr][squad] = l;
            split2(va1.x, h.x, l.x); split2(va1.y, h.y, l.y);
            split2(va1.z, h.z, l.z); split2(va1.w, h.w, l.w);
            *(ushort4*)&U.s.Ah[sr + 32][squad] = h;
            *(ushort4*)&U.s.Al[sr + 32][squad] = l;
            split2(vb0.x, h.x, l.x); split2(vb0.y, h.y, l.y);
            split2(vb0.z, h.z, l.z); split2(vb0.w, h.w, l.w);
            *(ushort4*)&U.s.Bh[sr][squad] = h;
            *(ushort4*)&U.s.Bl[sr][squad] = l;
            split2(vb1.x, h.x, l.x); split2(vb1.y, h.y, l.y);
            split2(vb1.z, h.z, l.z); split2(vb1.w, h.w, l.w);
            *(ushort4*)&U.s.Bh[sr + 32][squad] = h;
            *(ushort4*)&U.s.Bl[sr + 32][squad] = l;
        }
        __syncthreads();

        // prefetch next iteration (latency hides under frag reads + MFMA)
        if (k0 + BK < KCH) {
            va0 = *(const float4*)(Abase + (size_t)sr * K + k0 + BK);
            va1 = *(const float4*)(Abase + (size_t)(sr + 32) * K + k0 + BK);
            vb0 = *(const float4*)(Wbase + (size_t)sr * K + k0 + BK);
            vb1 = *(const float4*)(Wbase + (size_t)(sr + 32) * K + k0 + BK);
        }

        bf16x8 fah[2], fal[2], fbh[2], fbl[2];
        #pragma unroll
        for (int i = 0; i < 2; ++i) {
            const int row = wy * 32 + i * 16 + lr;
            fah[i] = *(const bf16x8*)&U.s.Ah[row][lg * 8];
            fal[i] = *(const bf16x8*)&U.s.Al[row][lg * 8];
        }
        #pragma unroll
        for (int j = 0; j < 2; ++j) {
            const int row = wx * 32 + j * 16 + lr;
            fbh[j] = *(const bf16x8*)&U.s.Bh[row][lg * 8];
            fbl[j] = *(const bf16x8*)&U.s.Bl[row][lg * 8];
        }
        #pragma unroll
        for (int i = 0; i < 2; ++i)
            #pragma unroll
            for (int j = 0; j < 2; ++j) {
                acc[i][j] = __builtin_amdgcn_mfma_f32_16x16x32_bf16(fah[i], fbh[j], acc[i][j], 0, 0, 0);
                acc[i][j] = __builtin_amdgcn_mfma_f32_16x16x32_bf16(fal[i], fbh[j], acc[i][j], 0, 0, 0);
                acc[i][j] = __builtin_amdgcn_mfma_f32_16x16x32_bf16(fah[i], fbl[j], acc[i][j], 0, 0, 0);
            }
    }

    // ---- epilogue: acc -> LDS transpose -> coalesced stores ----
    __syncthreads();   // staging LDS now reusable
    #pragma unroll
    for (int i = 0; i < 2; ++i)
        #pragma unroll
        for (int j = 0; j < 2; ++j) {
            const int col = wx * 32 + j * 16 + lr;
            const int rbase = wy * 32 + i * 16 + lg * 4;
            #pragma unroll
            for (int r = 0; r < 4; ++r)
                U.e.Ct[rbase + r][col] = acc[i][j][r];
        }
    __syncthreads();

    {
        const int cr = tid >> 4;          // 0..15
        const int cc = (tid & 15) * 4;    // 0..60
        #pragma unroll
        for (int q = 0; q < 4; ++q) {
            const int row = cr + q * 16;
            float4 v = *(const float4*)&U.e.Ct[row][cc];
            float* dst = &C[(size_t)(m0 + row) * COUT + o0 + cc];
            if (KSPLIT > 1) {
                atomicAdd(dst + 0, v.x); atomicAdd(dst + 1, v.y);
                atomicAdd(dst + 2, v.z); atomicAdd(dst + 3, v.w);
            } else {
                *(float4*)dst = v;
            }
        }
    }

    if constexpr (FUSE_STATS) {
        const int col = tid & 63, rq = tid >> 6;   // 4 threads per column
        float s = 0.f, q2 = 0.f;
        #pragma unroll
        for (int r = 0; r < 16; ++r) {
            float v = U.e.Ct[rq * 16 + r][col];
            s += v;
            q2 = fmaf(v, v, q2);
        }
        U.e.red[col][rq] = s;
        U.e.red[col][4 + rq] = q2;
        __syncthreads();
        if (tid < 64) {
            float ss = U.e.red[tid][0] + U.e.red[tid][1] + U.e.red[tid][2] + U.e.red[tid][3];
            float qq = U.e.red[tid][4] + U.e.red[tid][5] + U.e.red[tid][6] + U.e.red[tid][7];
            atomicAdd(&stats[o0 + tid], ss);
            atomicAdd(&stats[COUT + o0 + tid], qq);
        }
    }
}

// ---------------------------------------------------------------------------
// Column sums (per-channel sum & sumsq) -> atomics into out[0:256),[256:512).
// ---------------------------------------------------------------------------
__global__ __launch_bounds__(256)
void colsum256(const float* __restrict__ X, int rowsPerBlock,
               float* __restrict__ out) {
    const int c = threadIdx.x;
    const int r0 = blockIdx.x * rowsPerBlock;
    float s = 0.f, q = 0.f;
    for (int r = 0; r < rowsPerBlock; ++r) {
        float v = X[(size_t)(r0 + r) * COUT + c];
        s += v;
        q = fmaf(v, v, q);
    }
    atomicAdd(&out[c], s);
    atomicAdd(&out[COUT + c], q);
}

// ---------------------------------------------------------------------------
// three_nn phase 1: each block = 256 queries x one 128-point chunk.
// ---------------------------------------------------------------------------
__global__ __launch_bounds__(256)
void three_nn_part(const float* __restrict__ p1, const float* __restrict__ p2,
                   float2* __restrict__ part) {
    __shared__ float4 pts[CHUNK];
    const int b = blockIdx.z;
    const int c = blockIdx.y;
    const int t = threadIdx.x;
    const int n0 = c * CHUNK;
    if (t < CHUNK) {
        const float* P1 = p1 + ((size_t)b * NPTS + n0) * 3;
        float x = P1[t * 3 + 0], y = P1[t * 3 + 1], z = P1[t * 3 + 2];
        pts[t] = make_float4(x, y, z, x * x + y * y + z * z);
    }
    __syncthreads();
    const int m = blockIdx.x * 256 + t;
    const float* q = p2 + ((size_t)b * MPTS + m) * 3;
    const float qx = q[0], qy = q[1], qz = q[2];
    const float s2 = qx * qx + qy * qy + qz * qz;
    float d0 = 1e30f, d1 = 1e30f, d2 = 1e30f;
    int   i0 = 0,     i1 = 0,     i2 = 0;
    #pragma unroll 4
    for (int n = 0; n < CHUNK; ++n) {
        float4 p = pts[n];
        float dot = p.x * qx + p.y * qy + p.z * qz;
        float d = s2 + p.w - 2.0f * dot;   // same algebraic form as reference
        if (d < d2) {                      // strict '<': earliest index wins ties
            if (d < d1) {
                d2 = d1; i2 = i1;
                if (d < d0) { d1 = d0; i1 = i0; d0 = d; i0 = n0 + n; }
                else        { d1 = d;  i1 = n0 + n; }
            } else { d2 = d; i2 = n0 + n; }
        }
    }
    float2* o = part + ((size_t)(b * MPTS + m) * NCHUNK + c) * 3;
    o[0] = make_float2(d0, __int_as_float(i0));
    o[1] = make_float2(d1, __int_as_float(i1));
    o[2] = make_float2(d2, __int_as_float(i2));
}

// ---------------------------------------------------------------------------
// Final: merge NCHUNK top-3 partials (wave-uniform, redundant across the 64
// lanes of each row's wave), then
//   out[row][c] = relu(BN2(h2pre)) + sum_k w_k * relu(BN1(h1pre[idx_k][c]))
// float4-vectorized: 1 wave per row, 4 rows per block.
// stats layout: [0:256)=sum1 [256:512)=sq1 [512:768)=sum2 [768:1024)=sq2
// ---------------------------------------------------------------------------
__global__ __launch_bounds__(256)
void final_combine(const float* __restrict__ h1, const float* __restrict__ stats,
                   const float* __restrict__ g1, const float* __restrict__ b1,
                   const float* __restrict__ g2, const float* __restrict__ b2,
                   const float2* __restrict__ part, float* __restrict__ out) {
    const int t = threadIdx.x;
    const int row = blockIdx.x * 4 + (t >> 6);   // b*M + m
    const int c = (t & 63) * 4;
    const int b = row >> 13;                     // /8192

    // ---- wave-uniform merge of this row's partial top-3 lists ----
    float d0 = 1e30f, d1 = 1e30f, d2 = 1e30f;
    int   i0 = 0,     i1 = 0,     i2 = 0;
    {
        const float4* pp = (const float4*)(part + (size_t)row * NCHUNK * 3);
        #pragma unroll
        for (int j = 0; j < NCHUNK * 3 / 2; ++j) {    // 24 float4 = 48 pairs
            float4 v = pp[j];
            #pragma unroll
            for (int h = 0; h < 2; ++h) {
                float d = h ? v.z : v.x;
                int   i = __float_as_int(h ? v.w : v.y);
                if (d < d2) {
                    if (d < d1) {
                        d2 = d1; i2 = i1;
                        if (d < d0) { d1 = d0; i1 = i0; d0 = d; i0 = i; }
                        else        { d1 = d;  i1 = i; }
                    } else { d2 = d; i2 = i; }
                }
            }
        }
    }
    const float r0 = 1.0f / (d0 + NN_EPS);
    const float r1 = 1.0f / (d1 + NN_EPS);
    const float r2 = 1.0f / (d2 + NN_EPS);
    const float irs = 1.0f / (r0 + r1 + r2);
    const float w0 = r0 * irs, w1 = r1 * irs, w2 = r2 * irs;

    // ---- BN affines ----
    const float4 sum1 = *(const float4*)&stats[c];
    const float4 sq1  = *(const float4*)&stats[COUT + c];
    const float4 sum2 = *(const float4*)&stats[512 + c];
    const float4 sq2  = *(const float4*)&stats[768 + c];
    const float4 gg1  = *(const float4*)&g1[c];
    const float4 bb1  = *(const float4*)&b1[c];
    const float4 gg2  = *(const float4*)&g2[c];
    const float4 bb2  = *(const float4*)&b2[c];

    const float inv1 = 1.0f / (float)ROWS1, inv2 = 1.0f / (float)ROWS2;
    float4 sc1, sh1, sc2, sh2;
    {
        float m, v;
        m = sum1.x*inv1; v = fmaf(-m,m,sq1.x*inv1); sc1.x = gg1.x/sqrtf(v+BN_EPS); sh1.x = fmaf(-m,sc1.x,bb1.x);
        m = sum1.y*inv1; v = fmaf(-m,m,sq1.y*inv1); sc1.y = gg1.y/sqrtf(v+BN_EPS); sh1.y = fmaf(-m,sc1.y,bb1.y);
        m = sum1.z*inv1; v = fmaf(-m,m,sq1.z*inv1); sc1.z = gg1.z/sqrtf(v+BN_EPS); sh1.z = fmaf(-m,sc1.z,bb1.z);
        m = sum1.w*inv1; v = fmaf(-m,m,sq1.w*inv1); sc1.w = gg1.w/sqrtf(v+BN_EPS); sh1.w = fmaf(-m,sc1.w,bb1.w);
        m = sum2.x*inv2; v = fmaf(-m,m,sq2.x*inv2); sc2.x = gg2.x/sqrtf(v+BN_EPS); sh2.x = fmaf(-m,sc2.x,bb2.x);
        m = sum2.y*inv2; v = fmaf(-m,m,sq2.y*inv2); sc2.y = gg2.y/sqrtf(v+BN_EPS); sh2.y = fmaf(-m,sc2.y,bb2.y);
        m = sum2.z*inv2; v = fmaf(-m,m,sq2.z*inv2); sc2.z = gg2.z/sqrtf(v+BN_EPS); sh2.z = fmaf(-m,sc2.z,bb2.z);
        m = sum2.w*inv2; v = fmaf(-m,m,sq2.w*inv2); sc2.w = gg2.w/sqrtf(v+BN_EPS); sh2.w = fmaf(-m,sc2.w,bb2.w);
    }

    const float* hb = h1 + (size_t)b * NPTS * COUT + c;
    const float4 h0 = *(const float4*)(hb + (size_t)i0 * COUT);
    const float4 h4 = *(const float4*)(hb + (size_t)i1 * COUT);
    const float4 h8 = *(const float4*)(hb + (size_t)i2 * COUT);

    const size_t oi = (size_t)row * COUT + c;
    float4 yv = *(const float4*)&out[oi];
    float4 r;
    r.x = fmaxf(fmaf(yv.x, sc2.x, sh2.x), 0.f)
        + w0 * fmaxf(fmaf(h0.x, sc1.x, sh1.x), 0.f)
        + w1 * fmaxf(fmaf(h4.x, sc1.x, sh1.x), 0.f)
        + w2 * fmaxf(fmaf(h8.x, sc1.x, sh1.x), 0.f);
    r.y = fmaxf(fmaf(yv.y, sc2.y, sh2.y), 0.f)
        + w0 * fmaxf(fmaf(h0.y, sc1.y, sh1.y), 0.f)
        + w1 * fmaxf(fmaf(h4.y, sc1.y, sh1.y), 0.f)
        + w2 * fmaxf(fmaf(h8.y, sc1.y, sh1.y), 0.f);
    r.z = fmaxf(fmaf(yv.z, sc2.z, sh2.z), 0.f)
        + w0 * fmaxf(fmaf(h0.z, sc1.z, sh1.z), 0.f)
        + w1 * fmaxf(fmaf(h4.z, sc1.z, sh1.z), 0.f)
        + w2 * fmaxf(fmaf(h8.z, sc1.z, sh1.z), 0.f);
    r.w = fmaxf(fmaf(yv.w, sc2.w, sh2.w), 0.f)
        + w0 * fmaxf(fmaf(h0.w, sc1.w, sh1.w), 0.f)
        + w1 * fmaxf(fmaf(h4.w, sc1.w, sh1.w), 0.f)
        + w2 * fmaxf(fmaf(h8.w, sc1.w, sh1.w), 0.f);
    *(float4*)&out[oi] = r;
}

// ---------------------------------------------------------------------------
extern "C" void kernel_launch(void* const* d_in, const int* in_sizes, int n_in,
                              void* d_out, int out_size, void* d_ws, size_t ws_size,
                              hipStream_t stream) {
    const float* x1       = (const float*)d_in[0];  // (B,N,Cin1)
    const float* p1       = (const float*)d_in[1];  // (B,N,3)
    const float* x2       = (const float*)d_in[2];  // (B,M,Cin2)
    const float* p2       = (const float*)d_in[3];  // (B,M,3)
    const float* W_up     = (const float*)d_in[4];  // (COUT,CIN1)
    const float* gamma_up = (const float*)d_in[5];
    const float* beta_up  = (const float*)d_in[6];
    const float* W_lat    = (const float*)d_in[7];  // (COUT,CIN2)
    const float* gamma_lat= (const float*)d_in[8];
    const float* beta_lat = (const float*)d_in[9];
    float* out = (float*)d_out;

    // workspace layout (~11 MB)
    float*  h1    = (float*)d_ws;                        // ROWS1*COUT (pre-BN)
    float*  stats = h1 + (size_t)ROWS1 * COUT;           // 1024 floats
    float2* part  = (float2*)(stats + 1024);             // ROWS2*NCHUNK*3 float2

    hipMemsetAsync(stats, 0, 1024 * sizeof(float), stream);
    hipMemsetAsync(h1, 0, (size_t)ROWS1 * COUT * sizeof(float), stream);  // split-K acc

    // up_mlp GEMM (split-bf16 MFMA, split-K=4): 1024 blocks
    gemm_mfma64<CIN1, 4, false><<<dim3(COUT / 64, ROWS1 / 64, 4), 256, 0, stream>>>(
        x1, W_up, h1, nullptr);
    // BN1 stats from h1
    colsum256<<<256, 256, 0, stream>>>(h1, ROWS1 / 256, stats);

    // lateral GEMM into d_out's y region + fused BN2 stats: 1024 blocks
    gemm_mfma64<CIN2, 1, true><<<dim3(COUT / 64, ROWS2 / 64, 1), 256, 0, stream>>>(
        x2, W_lat, out, stats + 512);

    // 3-NN partials (merge is fused into final_combine)
    three_nn_part<<<dim3(MPTS / 256, NCHUNK, BATCH), 256, 0, stream>>>(p1, p2, part);

    // merge + gather-interp (+BN1+ReLU) + BN2 + ReLU + add, in place on d_out
    final_combine<<<ROWS2 / 4, 256, 0, stream>>>(h1, stats, gamma_up, beta_up,
                                                 gamma_lat, beta_lat, part, out);

    // p2 passthrough -> second output
    hipMemcpyAsync(out + (size_t)ROWS2 * COUT, p2,
                   (size_t)ROWS2 * 3 * sizeof(float),
                   hipMemcpyDeviceToDevice, stream);
}

// Round 6
// 194.676 us; speedup vs baseline: 1.2041x; 1.2041x over previous
//
#include <hip/hip_runtime.h>

// Problem constants (fixed by setup_inputs)
#define BATCH 2
#define NPTS  2048      // N (source points, x1/p1)
#define MPTS  8192      // M (query points, x2/p2)
#define CIN1  512       // Cin for up_mlp
#define CIN2  256       // Cin for lateral_mlp
#define COUT  256
#define ROWS1 (BATCH*NPTS)   // 4096
#define ROWS2 (BATCH*MPTS)   // 16384
#define BN_EPS 1e-5f
#define NN_EPS 1e-8f

// three_nn split-N decomposition
#define NCHUNK 16
#define CHUNK  (NPTS / NCHUNK)   // 128 points per chunk

typedef __attribute__((ext_vector_type(8))) short  bf16x8;  // 8 bf16 = 4 VGPRs
typedef __attribute__((ext_vector_type(4))) float  f32x4;   // MFMA acc

#define AS1 __attribute__((address_space(1)))
#define AS3 __attribute__((address_space(3)))

__device__ __forceinline__ unsigned short bf16_rne(float x) {
    unsigned u = __float_as_uint(x);
    u += 0x7FFFu + ((u >> 16) & 1u);
    return (unsigned short)(u >> 16);
}
__device__ __forceinline__ float bf16_f32(unsigned short h) {
    return __uint_as_float(((unsigned)h) << 16);
}

// global -> LDS DMA, 16 B per lane. LDS dest = wave-uniform base + lane*16;
// global src is per-lane (here: contiguous base + lane*16 -> fully coalesced).
__device__ __forceinline__ void gload16(const void* g, void* l) {
    __builtin_amdgcn_global_load_lds((const AS1 unsigned int*)g,
                                     (AS3 unsigned int*)l, 16, 0, 0);
}

// ---------------------------------------------------------------------------
// Pre-split: f32 matrices -> hi/lo bf16 "LDS tile images".
// Tile = 64 rows x 32 k, 4096 B per image tile, laid out so global_load_lds
// can stream it linearly.  Within a tile, element (row, k-chunk lg) lives at
// byte (row*64 + lg*16) ^ ((row&7)<<4)   [XOR swizzle per guide G4 — makes the
// GEMM's 16-lane column-slice ds_read_b128 2-way (free) instead of 8-way].
// One 256-thread block per tile: thread t -> row=t>>2, lg=t&3 (8 f32 -> 8+8 bf16).
// ---------------------------------------------------------------------------
__global__ __launch_bounds__(256)
void split_pre(const float* __restrict__ x1, const float* __restrict__ x2,
               const float* __restrict__ wu, const float* __restrict__ wl,
               unsigned short* __restrict__ x1h, unsigned short* __restrict__ x1l,
               unsigned short* __restrict__ x2h, unsigned short* __restrict__ x2l,
               unsigned short* __restrict__ wuh, unsigned short* __restrict__ wul,
               unsigned short* __restrict__ wlh, unsigned short* __restrict__ wll) {
    const int bid = blockIdx.x;
    const float* src; unsigned short *dh, *dl; int K, tile;
    if (bid < 1024)      { src = x1; dh = x1h; dl = x1l; K = CIN1; tile = bid; }
    else if (bid < 3072) { src = x2; dh = x2h; dl = x2l; K = CIN2; tile = bid - 1024; }
    else if (bid < 3136) { src = wu; dh = wuh; dl = wul; K = CIN1; tile = bid - 3072; }
    else                 { src = wl; dh = wlh; dl = wll; K = CIN2; tile = bid - 3136; }
    const int ktiles = K / 32;
    const int rt = tile / ktiles, kt = tile - rt * ktiles;
    const int t = threadIdx.x, row = t >> 2, lg = t & 3;

    const float* s = src + (size_t)(rt * 64 + row) * K + kt * 32 + lg * 8;
    const float4 v0 = *(const float4*)s;
    const float4 v1 = *(const float4*)(s + 4);
    const float vv[8] = {v0.x, v0.y, v0.z, v0.w, v1.x, v1.y, v1.z, v1.w};
    bf16x8 h, l;
    #pragma unroll
    for (int i = 0; i < 8; ++i) {
        const unsigned short hh = bf16_rne(vv[i]);
        h[i] = (short)hh;
        l[i] = (short)bf16_rne(vv[i] - bf16_f32(hh));
    }
    const unsigned off = ((unsigned)(row * 64 + lg * 16)) ^ ((unsigned)((row & 7) << 4));
    *(bf16x8*)((char*)dh + (size_t)tile * 4096 + off) = h;
    *(bf16x8*)((char*)dl + (size_t)tile * 4096 + off) = l;
}

// ---------------------------------------------------------------------------
// Split-bf16 MFMA GEMM (NT) on pre-split tile images.
// C = Ah*Bh + Al*Bh + Ah*Bl (3 passes of 16x16x32 bf16 MFMA).
// 64x64 tile, 256 threads = 4 waves (2x2), wave tile 32x32.
// k-loop = minimal 2-phase template: issue next-tile global_load_lds DMA,
// compute current from LDS, one vmcnt(0)+s_barrier per iteration (no
// __syncthreads -> no compiler-forced drain before compute).
// Wave w stages sub-buffer {Ah,Al,Bh,Bl}[w]: 4 KB = 4 DMA calls of 1 KB.
// KSPLIT>1: blockIdx.z = k-chunk, scalar atomicAdd into pre-zeroed C.
// FUSE_STATS: per-channel sum/sumsq -> atomicAdd stats (BN training stats).
// ---------------------------------------------------------------------------
template<int KTILES, int KSPLIT, bool FUSE_STATS>
__global__ __launch_bounds__(256)
void gemm_pre(const unsigned short* __restrict__ Ah_img, const unsigned short* __restrict__ Al_img,
              const unsigned short* __restrict__ Bh_img, const unsigned short* __restrict__ Bl_img,
              float* __restrict__ C, float* __restrict__ stats) {
    constexpr int KT = KTILES / KSPLIT;            // k-tiles this block
    __shared__ __align__(16) unsigned char lds[2][4][4096];   // [buf][Ah,Al,Bh,Bl]
    __shared__ float red[64][8];

    const int tid = threadIdx.x;
    const int lane = tid & 63, wid = tid >> 6;
    const int m0 = blockIdx.y * 64, o0 = blockIdx.x * 64;
    const int kt0 = blockIdx.z * KT;
    const int wy = wid >> 1, wx = wid & 1;
    const int lr = lane & 15, lg = lane >> 4;

    // this wave's staging stream (tile index = rowtile*KTILES + kt, 2048 ushorts)
    const unsigned short* src;
    size_t base;
    switch (wid) {
        case 0:  src = Ah_img; base = ((size_t)blockIdx.y * KTILES + kt0) * 2048; break;
        case 1:  src = Al_img; base = ((size_t)blockIdx.y * KTILES + kt0) * 2048; break;
        case 2:  src = Bh_img; base = ((size_t)blockIdx.x * KTILES + kt0) * 2048; break;
        default: src = Bl_img; base = ((size_t)blockIdx.x * KTILES + kt0) * 2048; break;
    }

    f32x4 acc[2][2];
    #pragma unroll
    for (int i = 0; i < 2; ++i)
        #pragma unroll
        for (int j = 0; j < 2; ++j)
            acc[i][j] = (f32x4){0.f, 0.f, 0.f, 0.f};

    auto STAGE = [&](int buf, int t) {
        const unsigned short* s = src + base + (size_t)t * 2048;
        char* l = (char*)&lds[buf][wid][0];
        #pragma unroll
        for (int c = 0; c < 4; ++c)
            gload16(s + c * 512 + lane * 8, l + c * 1024);
    };

    // frag byte offset inside a 4 KB sub-buffer (matches split_pre's swizzle)
    auto FOFF = [&](int row) -> int {
        return (row * 64 + lg * 16) ^ ((row & 7) << 4);
    };

    STAGE(0, 0);
    asm volatile("s_waitcnt vmcnt(0)" ::: "memory");
    __builtin_amdgcn_s_barrier();
    __builtin_amdgcn_sched_barrier(0);

    int cur = 0;
    for (int t = 0; t < KT; ++t) {
        if (t + 1 < KT) STAGE(cur ^ 1, t + 1);

        const char* LAh = (const char*)&lds[cur][0][0];
        const char* LAl = (const char*)&lds[cur][1][0];
        const char* LBh = (const char*)&lds[cur][2][0];
        const char* LBl = (const char*)&lds[cur][3][0];

        bf16x8 fah[2], fal[2], fbh[2], fbl[2];
        #pragma unroll
        for (int i = 0; i < 2; ++i) {
            const int off = FOFF(wy * 32 + i * 16 + lr);
            fah[i] = *(const bf16x8*)(LAh + off);
            fal[i] = *(const bf16x8*)(LAl + off);
        }
        #pragma unroll
        for (int j = 0; j < 2; ++j) {
            const int off = FOFF(wx * 32 + j * 16 + lr);
            fbh[j] = *(const bf16x8*)(LBh + off);
            fbl[j] = *(const bf16x8*)(LBl + off);
        }
        #pragma unroll
        for (int i = 0; i < 2; ++i)
            #pragma unroll
            for (int j = 0; j < 2; ++j) {
                acc[i][j] = __builtin_amdgcn_mfma_f32_16x16x32_bf16(fah[i], fbh[j], acc[i][j], 0, 0, 0);
                acc[i][j] = __builtin_amdgcn_mfma_f32_16x16x32_bf16(fal[i], fbh[j], acc[i][j], 0, 0, 0);
                acc[i][j] = __builtin_amdgcn_mfma_f32_16x16x32_bf16(fah[i], fbl[j], acc[i][j], 0, 0, 0);
            }

        asm volatile("s_waitcnt vmcnt(0)" ::: "memory");   // next-tile DMA done
        __builtin_amdgcn_s_barrier();                      // all sub-buffers visible
        __builtin_amdgcn_sched_barrier(0);
        cur ^= 1;
    }

    // C store: D lane mapping col = lane&15, row = (lane>>4)*4 + reg
    #pragma unroll
    for (int i = 0; i < 2; ++i)
        #pragma unroll
        for (int j = 0; j < 2; ++j) {
            const int col = o0 + wx * 32 + j * 16 + lr;
            const int rbase = m0 + wy * 32 + i * 16 + lg * 4;
            #pragma unroll
            for (int r = 0; r < 4; ++r) {
                if (KSPLIT > 1)
                    atomicAdd(&C[(size_t)(rbase + r) * COUT + col], acc[i][j][r]);
                else
                    C[(size_t)(rbase + r) * COUT + col] = acc[i][j][r];
            }
        }

    if constexpr (FUSE_STATS) {
        #pragma unroll
        for (int j = 0; j < 2; ++j) {
            float s = 0.f;
            #pragma unroll
            for (int i = 0; i < 2; ++i)
                #pragma unroll
                for (int r = 0; r < 4; ++r)
                    s += acc[i][j][r];
            red[wx * 32 + j * 16 + lr][wy * 4 + lg] = s;
        }
        __syncthreads();
        if (tid < 64) {
            float s = 0.f;
            #pragma unroll
            for (int k = 0; k < 8; ++k) s += red[tid][k];
            atomicAdd(&stats[o0 + tid], s);
        }
        __syncthreads();
        #pragma unroll
        for (int j = 0; j < 2; ++j) {
            float q = 0.f;
            #pragma unroll
            for (int i = 0; i < 2; ++i)
                #pragma unroll
                for (int r = 0; r < 4; ++r)
                    q = fmaf(acc[i][j][r], acc[i][j][r], q);
            red[wx * 32 + j * 16 + lr][wy * 4 + lg] = q;
        }
        __syncthreads();
        if (tid < 64) {
            float q = 0.f;
            #pragma unroll
            for (int k = 0; k < 8; ++k) q += red[tid][k];
            atomicAdd(&stats[COUT + o0 + tid], q);
        }
    }
}

// ---------------------------------------------------------------------------
// Column sums (per-channel sum & sumsq) -> atomics into out[0:256),[256:512).
// ---------------------------------------------------------------------------
__global__ __launch_bounds__(256)
void colsum256(const float* __restrict__ X, int rowsPerBlock,
               float* __restrict__ out) {
    const int c = threadIdx.x;
    const int r0 = blockIdx.x * rowsPerBlock;
    float s = 0.f, q = 0.f;
    for (int r = 0; r < rowsPerBlock; ++r) {
        float v = X[(size_t)(r0 + r) * COUT + c];
        s += v;
        q = fmaf(v, v, q);
    }
    atomicAdd(&out[c], s);
    atomicAdd(&out[COUT + c], q);
}

// ---------------------------------------------------------------------------
// three_nn phase 1: each block = 256 queries x one 128-point chunk.
// ---------------------------------------------------------------------------
__global__ __launch_bounds__(256)
void three_nn_part(const float* __restrict__ p1, const float* __restrict__ p2,
                   float2* __restrict__ part) {
    __shared__ float4 pts[CHUNK];
    const int b = blockIdx.z;
    const int c = blockIdx.y;
    const int t = threadIdx.x;
    const int n0 = c * CHUNK;
    if (t < CHUNK) {
        const float* P1 = p1 + ((size_t)b * NPTS + n0) * 3;
        float x = P1[t * 3 + 0], y = P1[t * 3 + 1], z = P1[t * 3 + 2];
        pts[t] = make_float4(x, y, z, x * x + y * y + z * z);
    }
    __syncthreads();
    const int m = blockIdx.x * 256 + t;
    const float* q = p2 + ((size_t)b * MPTS + m) * 3;
    const float qx = q[0], qy = q[1], qz = q[2];
    const float s2 = qx * qx + qy * qy + qz * qz;
    float d0 = 1e30f, d1 = 1e30f, d2 = 1e30f;
    int   i0 = 0,     i1 = 0,     i2 = 0;
    #pragma unroll 4
    for (int n = 0; n < CHUNK; ++n) {
        float4 p = pts[n];
        float dot = p.x * qx + p.y * qy + p.z * qz;
        float d = s2 + p.w - 2.0f * dot;   // same algebraic form as reference
        if (d < d2) {                      // strict '<': earliest index wins ties
            if (d < d1) {
                d2 = d1; i2 = i1;
                if (d < d0) { d1 = d0; i1 = i0; d0 = d; i0 = n0 + n; }
                else        { d1 = d;  i1 = n0 + n; }
            } else { d2 = d; i2 = n0 + n; }
        }
    }
    float2* o = part + ((size_t)(b * MPTS + m) * NCHUNK + c) * 3;
    o[0] = make_float2(d0, __int_as_float(i0));
    o[1] = make_float2(d1, __int_as_float(i1));
    o[2] = make_float2(d2, __int_as_float(i2));
}

// ---------------------------------------------------------------------------
// Final: merge NCHUNK top-3 partials (wave-uniform, broadcast loads), then
//   out[row][c] = relu(BN2(h2pre)) + sum_k w_k * relu(BN1(h1pre[idx_k][c]))
// float4-vectorized: 1 wave per row, 4 rows per block.
// stats layout: [0:256)=sum1 [256:512)=sq1 [512:768)=sum2 [768:1024)=sq2
// ---------------------------------------------------------------------------
__global__ __launch_bounds__(256)
void final_combine(const float* __restrict__ h1, const float* __restrict__ stats,
                   const float* __restrict__ g1, const float* __restrict__ b1,
                   const float* __restrict__ g2, const float* __restrict__ b2,
                   const float2* __restrict__ part, float* __restrict__ out) {
    const int t = threadIdx.x;
    const int row = blockIdx.x * 4 + (t >> 6);   // b*M + m
    const int c = (t & 63) * 4;
    const int b = row >> 13;                     // /8192

    float d0 = 1e30f, d1 = 1e30f, d2 = 1e30f;
    int   i0 = 0,     i1 = 0,     i2 = 0;
    {
        const float4* pp = (const float4*)(part + (size_t)row * NCHUNK * 3);
        #pragma unroll
        for (int j = 0; j < NCHUNK * 3 / 2; ++j) {    // 24 float4 = 48 pairs
            float4 v = pp[j];
            #pragma unroll
            for (int h = 0; h < 2; ++h) {
                float d = h ? v.z : v.x;
                int   i = __float_as_int(h ? v.w : v.y);
                if (d < d2) {
                    if (d < d1) {
                        d2 = d1; i2 = i1;
                        if (d < d0) { d1 = d0; i1 = i0; d0 = d; i0 = i; }
                        else        { d1 = d;  i1 = i; }
                    } else { d2 = d; i2 = i; }
                }
            }
        }
    }
    const float r0 = 1.0f / (d0 + NN_EPS);
    const float r1 = 1.0f / (d1 + NN_EPS);
    const float r2 = 1.0f / (d2 + NN_EPS);
    const float irs = 1.0f / (r0 + r1 + r2);
    const float w0 = r0 * irs, w1 = r1 * irs, w2 = r2 * irs;

    const float4 sum1 = *(const float4*)&stats[c];
    const float4 sq1  = *(const float4*)&stats[COUT + c];
    const float4 sum2 = *(const float4*)&stats[512 + c];
    const float4 sq2  = *(const float4*)&stats[768 + c];
    const float4 gg1  = *(const float4*)&g1[c];
    const float4 bb1  = *(const float4*)&b1[c];
    const float4 gg2  = *(const float4*)&g2[c];
    const float4 bb2  = *(const float4*)&b2[c];

    const float inv1 = 1.0f / (float)ROWS1, inv2 = 1.0f / (float)ROWS2;
    float4 sc1, sh1, sc2, sh2;
    {
        float m, v;
        m = sum1.x*inv1; v = fmaf(-m,m,sq1.x*inv1); sc1.x = gg1.x/sqrtf(v+BN_EPS); sh1.x = fmaf(-m,sc1.x,bb1.x);
        m = sum1.y*inv1; v = fmaf(-m,m,sq1.y*inv1); sc1.y = gg1.y/sqrtf(v+BN_EPS); sh1.y = fmaf(-m,sc1.y,bb1.y);
        m = sum1.z*inv1; v = fmaf(-m,m,sq1.z*inv1); sc1.z = gg1.z/sqrtf(v+BN_EPS); sh1.z = fmaf(-m,sc1.z,bb1.z);
        m = sum1.w*inv1; v = fmaf(-m,m,sq1.w*inv1); sc1.w = gg1.w/sqrtf(v+BN_EPS); sh1.w = fmaf(-m,sc1.w,bb1.w);
        m = sum2.x*inv2; v = fmaf(-m,m,sq2.x*inv2); sc2.x = gg2.x/sqrtf(v+BN_EPS); sh2.x = fmaf(-m,sc2.x,bb2.x);
        m = sum2.y*inv2; v = fmaf(-m,m,sq2.y*inv2); sc2.y = gg2.y/sqrtf(v+BN_EPS); sh2.y = fmaf(-m,sc2.y,bb2.y);
        m = sum2.z*inv2; v = fmaf(-m,m,sq2.z*inv2); sc2.z = gg2.z/sqrtf(v+BN_EPS); sh2.z = fmaf(-m,sc2.z,bb2.z);
        m = sum2.w*inv2; v = fmaf(-m,m,sq2.w*inv2); sc2.w = gg2.w/sqrtf(v+BN_EPS); sh2.w = fmaf(-m,sc2.w,bb2.w);
    }

    const float* hb = h1 + (size_t)b * NPTS * COUT + c;
    const float4 h0 = *(const float4*)(hb + (size_t)i0 * COUT);
    const float4 h4 = *(const float4*)(hb + (size_t)i1 * COUT);
    const float4 h8 = *(const float4*)(hb + (size_t)i2 * COUT);

    const size_t oi = (size_t)row * COUT + c;
    float4 yv = *(const float4*)&out[oi];
    float4 r;
    r.x = fmaxf(fmaf(yv.x, sc2.x, sh2.x), 0.f)
        + w0 * fmaxf(fmaf(h0.x, sc1.x, sh1.x), 0.f)
        + w1 * fmaxf(fmaf(h4.x, sc1.x, sh1.x), 0.f)
        + w2 * fmaxf(fmaf(h8.x, sc1.x, sh1.x), 0.f);
    r.y = fmaxf(fmaf(yv.y, sc2.y, sh2.y), 0.f)
        + w0 * fmaxf(fmaf(h0.y, sc1.y, sh1.y), 0.f)
        + w1 * fmaxf(fmaf(h4.y, sc1.y, sh1.y), 0.f)
        + w2 * fmaxf(fmaf(h8.y, sc1.y, sh1.y), 0.f);
    r.z = fmaxf(fmaf(yv.z, sc2.z, sh2.z), 0.f)
        + w0 * fmaxf(fmaf(h0.z, sc1.z, sh1.z), 0.f)
        + w1 * fmaxf(fmaf(h4.z, sc1.z, sh1.z), 0.f)
        + w2 * fmaxf(fmaf(h8.z, sc1.z, sh1.z), 0.f);
    r.w = fmaxf(fmaf(yv.w, sc2.w, sh2.w), 0.f)
        + w0 * fmaxf(fmaf(h0.w, sc1.w, sh1.w), 0.f)
        + w1 * fmaxf(fmaf(h4.w, sc1.w, sh1.w), 0.f)
        + w2 * fmaxf(fmaf(h8.w, sc1.w, sh1.w), 0.f);
    *(float4*)&out[oi] = r;
}

// ---------------------------------------------------------------------------
extern "C" void kernel_launch(void* const* d_in, const int* in_sizes, int n_in,
                              void* d_out, int out_size, void* d_ws, size_t ws_size,
                              hipStream_t stream) {
    const float* x1       = (const float*)d_in[0];  // (B,N,Cin1)
    const float* p1       = (const float*)d_in[1];  // (B,N,3)
    const float* x2       = (const float*)d_in[2];  // (B,M,Cin2)
    const float* p2       = (const float*)d_in[3];  // (B,M,3)
    const float* W_up     = (const float*)d_in[4];  // (COUT,CIN1)
    const float* gamma_up = (const float*)d_in[5];
    const float* beta_up  = (const float*)d_in[6];
    const float* W_lat    = (const float*)d_in[7];  // (COUT,CIN2)
    const float* gamma_lat= (const float*)d_in[8];
    const float* beta_lat = (const float*)d_in[9];
    float* out = (float*)d_out;

    // workspace layout (~35 MB)
    char* w = (char*)d_ws;
    unsigned short* x1h = (unsigned short*)(w);                 // 4 MB (1024 tiles)
    unsigned short* x1l = (unsigned short*)(w + (4u<<20));      // 4 MB
    unsigned short* x2h = (unsigned short*)(w + (8u<<20));      // 8 MB (2048 tiles)
    unsigned short* x2l = (unsigned short*)(w + (16u<<20));     // 8 MB
    unsigned short* wuh = (unsigned short*)(w + (24u<<20));     // 256 KB (64 tiles)
    unsigned short* wul = (unsigned short*)(w + (24u<<20) + (256u<<10));
    unsigned short* wlh = (unsigned short*)(w + (24u<<20) + (512u<<10)); // 128 KB (32)
    unsigned short* wll = (unsigned short*)(w + (24u<<20) + (640u<<10));
    float*  h1    = (float*)(w + (25u<<20));                    // 4 MB
    float*  stats = (float*)(w + (29u<<20));                    // 4 KB
    float2* part  = (float2*)(w + (29u<<20) + (16u<<10));       // ~6.3 MB

    hipMemsetAsync(stats, 0, 1024 * sizeof(float), stream);
    hipMemsetAsync(h1, 0, (size_t)ROWS1 * COUT * sizeof(float), stream);  // split-K acc

    // pre-split all four f32 matrices into hi/lo bf16 tile images
    split_pre<<<3168, 256, 0, stream>>>(x1, x2, W_up, W_lat,
                                        x1h, x1l, x2h, x2l, wuh, wul, wlh, wll);

    // up_mlp GEMM (split-K=4): grid 1024
    gemm_pre<CIN1/32, 4, false><<<dim3(COUT/64, ROWS1/64, 4), 256, 0, stream>>>(
        x1h, x1l, wuh, wul, h1, nullptr);
    // BN1 stats from h1
    colsum256<<<256, 256, 0, stream>>>(h1, ROWS1 / 256, stats);

    // lateral GEMM into d_out's y region + fused BN2 stats: grid 1024
    gemm_pre<CIN2/32, 1, true><<<dim3(COUT/64, ROWS2/64, 1), 256, 0, stream>>>(
        x2h, x2l, wlh, wll, out, stats + 512);

    // 3-NN partials (merge fused into final_combine)
    three_nn_part<<<dim3(MPTS / 256, NCHUNK, BATCH), 256, 0, stream>>>(p1, p2, part);

    // merge + gather-interp (+BN1+ReLU) + BN2 + ReLU + add, in place on d_out
    final_combine<<<ROWS2 / 4, 256, 0, stream>>>(h1, stats, gamma_up, beta_up,
                                                 gamma_lat, beta_lat, part, out);

    // p2 passthrough -> second output
    hipMemcpyAsync(out + (size_t)ROWS2 * COUT, p2,
                   (size_t)ROWS2 * 3 * sizeof(float),
                   hipMemcpyDeviceToDevice, stream);
}

// Round 7
// 192.194 us; speedup vs baseline: 1.2197x; 1.0129x over previous
//
#include <hip/hip_runtime.h>

// Problem constants (fixed by setup_inputs)
#define BATCH 2
#define NPTS  2048
#define MPTS  8192
#define CIN1  512
#define CIN2  256
#define COUT  256
#define ROWS1 (BATCH*NPTS)   // 4096
#define ROWS2 (BATCH*MPTS)   // 16384
#define BN_EPS 1e-5f
#define NN_EPS 1e-8f

#define NCHUNK 16
#define CHUNK  (NPTS / NCHUNK)   // 128

typedef __attribute__((ext_vector_type(8))) short  bf16x8;
typedef __attribute__((ext_vector_type(4))) float  f32x4;

#define AS1 __attribute__((address_space(1)))
#define AS3 __attribute__((address_space(3)))

__device__ __forceinline__ unsigned short bf16_rne(float x) {
    unsigned u = __float_as_uint(x);
    u += 0x7FFFu + ((u >> 16) & 1u);
    return (unsigned short)(u >> 16);
}
__device__ __forceinline__ float bf16_f32(unsigned short h) {
    return __uint_as_float(((unsigned)h) << 16);
}
__device__ __forceinline__ void gload16(const void* g, void* l) {
    __builtin_amdgcn_global_load_lds((const AS1 unsigned int*)g,
                                     (AS3 unsigned int*)l, 16, 0, 0);
}

// ---------------------------------------------------------------------------
// K1: fused {pre-split to swizzled bf16 hi/lo tile images} + {three_nn partials}
// split tile = 64 rows x 32 k, 4096 B; element (row, k-octet lg) at byte
// (row*64 + lg*16) ^ ((row&7)<<4)  [G4 XOR swizzle, baked into the image].
// ---------------------------------------------------------------------------
__global__ __launch_bounds__(256)
void prep_fused(const float* __restrict__ x1, const float* __restrict__ x2,
                const float* __restrict__ wu, const float* __restrict__ wl,
                const float* __restrict__ p1, const float* __restrict__ p2,
                unsigned short* __restrict__ x1h, unsigned short* __restrict__ x1l,
                unsigned short* __restrict__ x2h, unsigned short* __restrict__ x2l,
                unsigned short* __restrict__ wuh, unsigned short* __restrict__ wul,
                unsigned short* __restrict__ wlh, unsigned short* __restrict__ wll,
                float2* __restrict__ part) {
    const int bid = blockIdx.x;
    const int t = threadIdx.x;
    if (bid < 3168) {
        // ---------------- split_pre ----------------
        const float* src; unsigned short *dh, *dl; int K, tile;
        if (bid < 1024)      { src = x1; dh = x1h; dl = x1l; K = CIN1; tile = bid; }
        else if (bid < 3072) { src = x2; dh = x2h; dl = x2l; K = CIN2; tile = bid - 1024; }
        else if (bid < 3136) { src = wu; dh = wuh; dl = wul; K = CIN1; tile = bid - 3072; }
        else                 { src = wl; dh = wlh; dl = wll; K = CIN2; tile = bid - 3136; }
        const int ktiles = K / 32;
        const int rt = tile / ktiles, kt = tile - rt * ktiles;
        const int row = t >> 2, lg = t & 3;
        const float* s = src + (size_t)(rt * 64 + row) * K + kt * 32 + lg * 8;
        const float4 v0 = *(const float4*)s;
        const float4 v1 = *(const float4*)(s + 4);
        const float vv[8] = {v0.x, v0.y, v0.z, v0.w, v1.x, v1.y, v1.z, v1.w};
        bf16x8 h, l;
        #pragma unroll
        for (int i = 0; i < 8; ++i) {
            const unsigned short hh = bf16_rne(vv[i]);
            h[i] = (short)hh;
            l[i] = (short)bf16_rne(vv[i] - bf16_f32(hh));
        }
        const unsigned off = ((unsigned)(row * 64 + lg * 16)) ^ ((unsigned)((row & 7) << 4));
        *(bf16x8*)((char*)dh + (size_t)tile * 4096 + off) = h;
        *(bf16x8*)((char*)dl + (size_t)tile * 4096 + off) = l;
    } else {
        // ---------------- three_nn partials ----------------
        __shared__ float4 pts[CHUNK];
        const int q = bid - 3168;
        const int b = q >> 9;              // batch
        const int r = q & 511;
        const int ck = r >> 5;             // chunk 0..15
        const int mblk = r & 31;           // query block 0..31
        const int n0 = ck * CHUNK;
        if (t < CHUNK) {
            const float* P1 = p1 + ((size_t)b * NPTS + n0) * 3;
            float x = P1[t * 3 + 0], y = P1[t * 3 + 1], z = P1[t * 3 + 2];
            pts[t] = make_float4(x, y, z, x * x + y * y + z * z);
        }
        __syncthreads();
        const int m = mblk * 256 + t;
        const float* qp = p2 + ((size_t)b * MPTS + m) * 3;
        const float qx = qp[0], qy = qp[1], qz = qp[2];
        const float s2 = qx * qx + qy * qy + qz * qz;
        float d0 = 1e30f, d1 = 1e30f, d2 = 1e30f;
        int   i0 = 0,     i1 = 0,     i2 = 0;
        #pragma unroll 4
        for (int n = 0; n < CHUNK; ++n) {
            float4 p = pts[n];
            float dot = p.x * qx + p.y * qy + p.z * qz;
            float d = s2 + p.w - 2.0f * dot;   // same algebraic form as reference
            if (d < d2) {                      // strict '<': earliest index wins ties
                if (d < d1) {
                    d2 = d1; i2 = i1;
                    if (d < d0) { d1 = d0; i1 = i0; d0 = d; i0 = n0 + n; }
                    else        { d1 = d;  i1 = n0 + n; }
                } else { d2 = d; i2 = n0 + n; }
            }
        }
        float2* o = part + ((size_t)(b * MPTS + m) * NCHUNK + ck) * 3;
        o[0] = make_float2(d0, __int_as_float(i0));
        o[1] = make_float2(d1, __int_as_float(i1));
        o[2] = make_float2(d2, __int_as_float(i2));
    }
}

// ---------------------------------------------------------------------------
// GEMM body: split-bf16 MFMA on pre-swizzled tile images.
// 3-buffer LDS pipeline, counted vmcnt(4) (T4): stage t+1 stays in flight
// across the barrier; stage t+2 issued right after it.  One barrier/iter.
// ---------------------------------------------------------------------------
struct GemmLds {
    unsigned char buf[3][4][4096];   // [stage%3][Ah,Al,Bh,Bl]  48 KB
    float red[64][8];
};

template<int KTILES, int KSPLIT, bool FUSE_STATS>
__device__ __forceinline__ void gemm_body(
        const unsigned short* __restrict__ Ah_img, const unsigned short* __restrict__ Al_img,
        const unsigned short* __restrict__ Bh_img, const unsigned short* __restrict__ Bl_img,
        float* __restrict__ C, float* __restrict__ stats,
        int bx, int by, int bz, GemmLds& S) {
    constexpr int KT = KTILES / KSPLIT;
    const int tid = threadIdx.x;
    const int lane = tid & 63, wid = tid >> 6;
    const int m0 = by * 64, o0 = bx * 64;
    const int kt0 = bz * KT;
    const int wy = wid >> 1, wx = wid & 1;
    const int lr = lane & 15, lg = lane >> 4;

    const unsigned short* src;
    size_t base;
    switch (wid) {
        case 0:  src = Ah_img; base = ((size_t)by * KTILES + kt0) * 2048; break;
        case 1:  src = Al_img; base = ((size_t)by * KTILES + kt0) * 2048; break;
        case 2:  src = Bh_img; base = ((size_t)bx * KTILES + kt0) * 2048; break;
        default: src = Bl_img; base = ((size_t)bx * KTILES + kt0) * 2048; break;
    }

    f32x4 acc[2][2];
    #pragma unroll
    for (int i = 0; i < 2; ++i)
        #pragma unroll
        for (int j = 0; j < 2; ++j)
            acc[i][j] = (f32x4){0.f, 0.f, 0.f, 0.f};

    auto STAGE = [&](int buf, int tt) {
        const unsigned short* s = src + base + (size_t)tt * 2048;
        char* l = (char*)&S.buf[buf][wid][0];
        #pragma unroll
        for (int c = 0; c < 4; ++c)
            gload16(s + c * 512 + (size_t)lane * 8, l + c * 1024);
    };
    auto FOFF = [&](int row) -> int {
        return (row * 64 + lg * 16) ^ ((row & 7) << 4);
    };

    STAGE(0, 0);
    if (KT > 1) STAGE(1, 1);

    for (int t = 0; t < KT; ++t) {
        if (t + 1 < KT) asm volatile("s_waitcnt vmcnt(4)" ::: "memory");
        else            asm volatile("s_waitcnt vmcnt(0)" ::: "memory");
        __builtin_amdgcn_s_barrier();
        __builtin_amdgcn_sched_barrier(0);
        if (t + 2 < KT) STAGE((t + 2) % 3, t + 2);

        const int cb = t % 3;
        const char* LAh = (const char*)&S.buf[cb][0][0];
        const char* LAl = (const char*)&S.buf[cb][1][0];
        const char* LBh = (const char*)&S.buf[cb][2][0];
        const char* LBl = (const char*)&S.buf[cb][3][0];

        bf16x8 fah[2], fal[2], fbh[2], fbl[2];
        #pragma unroll
        for (int i = 0; i < 2; ++i) {
            const int off = FOFF(wy * 32 + i * 16 + lr);
            fah[i] = *(const bf16x8*)(LAh + off);
            fal[i] = *(const bf16x8*)(LAl + off);
        }
        #pragma unroll
        for (int j = 0; j < 2; ++j) {
            const int off = FOFF(wx * 32 + j * 16 + lr);
            fbh[j] = *(const bf16x8*)(LBh + off);
            fbl[j] = *(const bf16x8*)(LBl + off);
        }
        #pragma unroll
        for (int i = 0; i < 2; ++i)
            #pragma unroll
            for (int j = 0; j < 2; ++j) {
                acc[i][j] = __builtin_amdgcn_mfma_f32_16x16x32_bf16(fah[i], fbh[j], acc[i][j], 0, 0, 0);
                acc[i][j] = __builtin_amdgcn_mfma_f32_16x16x32_bf16(fal[i], fbh[j], acc[i][j], 0, 0, 0);
                acc[i][j] = __builtin_amdgcn_mfma_f32_16x16x32_bf16(fah[i], fbl[j], acc[i][j], 0, 0, 0);
            }
    }

    // C store: D lane mapping col = lane&15, row = (lane>>4)*4 + reg
    #pragma unroll
    for (int i = 0; i < 2; ++i)
        #pragma unroll
        for (int j = 0; j < 2; ++j) {
            const int col = o0 + wx * 32 + j * 16 + lr;
            const int rbase = m0 + wy * 32 + i * 16 + lg * 4;
            #pragma unroll
            for (int r = 0; r < 4; ++r) {
                if (KSPLIT > 1)
                    atomicAdd(&C[(size_t)(rbase + r) * COUT + col], acc[i][j][r]);
                else
                    C[(size_t)(rbase + r) * COUT + col] = acc[i][j][r];
            }
        }

    if constexpr (FUSE_STATS) {
        #pragma unroll
        for (int j = 0; j < 2; ++j) {
            float s = 0.f;
            #pragma unroll
            for (int i = 0; i < 2; ++i)
                #pragma unroll
                for (int r = 0; r < 4; ++r)
                    s += acc[i][j][r];
            S.red[wx * 32 + j * 16 + lr][wy * 4 + lg] = s;
        }
        __syncthreads();
        if (tid < 64) {
            float s = 0.f;
            #pragma unroll
            for (int k = 0; k < 8; ++k) s += S.red[tid][k];
            atomicAdd(&stats[o0 + tid], s);
        }
        __syncthreads();
        #pragma unroll
        for (int j = 0; j < 2; ++j) {
            float q = 0.f;
            #pragma unroll
            for (int i = 0; i < 2; ++i)
                #pragma unroll
                for (int r = 0; r < 4; ++r)
                    q = fmaf(acc[i][j][r], acc[i][j][r], q);
            S.red[wx * 32 + j * 16 + lr][wy * 4 + lg] = q;
        }
        __syncthreads();
        if (tid < 64) {
            float q = 0.f;
            #pragma unroll
            for (int k = 0; k < 8; ++k) q += S.red[tid][k];
            atomicAdd(&stats[COUT + o0 + tid], q);
        }
    }
}

// K2: both GEMMs in one 2048-block launch (independent -> cross-gemm TLP).
// blocks [0,1024): gemm2 (lateral, fused BN2 stats) ; [1024,2048): gemm1 splitK=4.
__global__ __launch_bounds__(256)
void gemm_fused(const unsigned short* __restrict__ x1h, const unsigned short* __restrict__ x1l,
                const unsigned short* __restrict__ wuh, const unsigned short* __restrict__ wul,
                const unsigned short* __restrict__ x2h, const unsigned short* __restrict__ x2l,
                const unsigned short* __restrict__ wlh, const unsigned short* __restrict__ wll,
                float* __restrict__ h1, float* __restrict__ out, float* __restrict__ stats) {
    __shared__ GemmLds S;
    const int bid = blockIdx.x;
    if (bid < 1024) {
        gemm_body<CIN2/32, 1, true>(x2h, x2l, wlh, wll, out, stats + 512,
                                    bid & 3, bid >> 2, 0, S);
    } else {
        const int q = bid - 1024;
        gemm_body<CIN1/32, 4, false>(x1h, x1l, wuh, wul, h1, nullptr,
                                     q & 3, (q & 255) >> 2, q >> 8, S);
    }
}

// ---------------------------------------------------------------------------
// Column sums (per-channel sum & sumsq) -> atomics (BN1 stats after splitK).
// ---------------------------------------------------------------------------
__global__ __launch_bounds__(256)
void colsum256(const float* __restrict__ X, int rowsPerBlock,
               float* __restrict__ out) {
    const int c = threadIdx.x;
    const int r0 = blockIdx.x * rowsPerBlock;
    float s = 0.f, q = 0.f;
    for (int r = 0; r < rowsPerBlock; ++r) {
        float v = X[(size_t)(r0 + r) * COUT + c];
        s += v;
        q = fmaf(v, v, q);
    }
    atomicAdd(&out[c], s);
    atomicAdd(&out[COUT + c], q);
}

// ---------------------------------------------------------------------------
// Final: wave-uniform merge of NCHUNK top-3 partials + gather-interp
// (+BN1+ReLU) + BN2 + ReLU + add, in place on d_out.
// ---------------------------------------------------------------------------
__global__ __launch_bounds__(256)
void final_combine(const float* __restrict__ h1, const float* __restrict__ stats,
                   const float* __restrict__ g1, const float* __restrict__ b1,
                   const float* __restrict__ g2, const float* __restrict__ b2,
                   const float2* __restrict__ part, float* __restrict__ out) {
    const int t = threadIdx.x;
    const int row = blockIdx.x * 4 + (t >> 6);
    const int c = (t & 63) * 4;
    const int b = row >> 13;

    float d0 = 1e30f, d1 = 1e30f, d2 = 1e30f;
    int   i0 = 0,     i1 = 0,     i2 = 0;
    {
        const float4* pp = (const float4*)(part + (size_t)row * NCHUNK * 3);
        #pragma unroll
        for (int j = 0; j < NCHUNK * 3 / 2; ++j) {
            float4 v = pp[j];
            #pragma unroll
            for (int h = 0; h < 2; ++h) {
                float d = h ? v.z : v.x;
                int   i = __float_as_int(h ? v.w : v.y);
                if (d < d2) {
                    if (d < d1) {
                        d2 = d1; i2 = i1;
                        if (d < d0) { d1 = d0; i1 = i0; d0 = d; i0 = i; }
                        else        { d1 = d;  i1 = i; }
                    } else { d2 = d; i2 = i; }
                }
            }
        }
    }
    const float r0 = 1.0f / (d0 + NN_EPS);
    const float r1 = 1.0f / (d1 + NN_EPS);
    const float r2 = 1.0f / (d2 + NN_EPS);
    const float irs = 1.0f / (r0 + r1 + r2);
    const float w0 = r0 * irs, w1 = r1 * irs, w2 = r2 * irs;

    const float4 sum1 = *(const float4*)&stats[c];
    const float4 sq1  = *(const float4*)&stats[COUT + c];
    const float4 sum2 = *(const float4*)&stats[512 + c];
    const float4 sq2  = *(const float4*)&stats[768 + c];
    const float4 gg1  = *(const float4*)&g1[c];
    const float4 bb1  = *(const float4*)&b1[c];
    const float4 gg2  = *(const float4*)&g2[c];
    const float4 bb2  = *(const float4*)&b2[c];

    const float inv1 = 1.0f / (float)ROWS1, inv2 = 1.0f / (float)ROWS2;
    float4 sc1, sh1, sc2, sh2;
    {
        float m, v;
        m = sum1.x*inv1; v = fmaf(-m,m,sq1.x*inv1); sc1.x = gg1.x/sqrtf(v+BN_EPS); sh1.x = fmaf(-m,sc1.x,bb1.x);
        m = sum1.y*inv1; v = fmaf(-m,m,sq1.y*inv1); sc1.y = gg1.y/sqrtf(v+BN_EPS); sh1.y = fmaf(-m,sc1.y,bb1.y);
        m = sum1.z*inv1; v = fmaf(-m,m,sq1.z*inv1); sc1.z = gg1.z/sqrtf(v+BN_EPS); sh1.z = fmaf(-m,sc1.z,bb1.z);
        m = sum1.w*inv1; v = fmaf(-m,m,sq1.w*inv1); sc1.w = gg1.w/sqrtf(v+BN_EPS); sh1.w = fmaf(-m,sc1.w,bb1.w);
        m = sum2.x*inv2; v = fmaf(-m,m,sq2.x*inv2); sc2.x = gg2.x/sqrtf(v+BN_EPS); sh2.x = fmaf(-m,sc2.x,bb2.x);
        m = sum2.y*inv2; v = fmaf(-m,m,sq2.y*inv2); sc2.y = gg2.y/sqrtf(v+BN_EPS); sh2.y = fmaf(-m,sc2.y,bb2.y);
        m = sum2.z*inv2; v = fmaf(-m,m,sq2.z*inv2); sc2.z = gg2.z/sqrtf(v+BN_EPS); sh2.z = fmaf(-m,sc2.z,bb2.z);
        m = sum2.w*inv2; v = fmaf(-m,m,sq2.w*inv2); sc2.w = gg2.w/sqrtf(v+BN_EPS); sh2.w = fmaf(-m,sc2.w,bb2.w);
    }

    const float* hb = h1 + (size_t)b * NPTS * COUT + c;
    const float4 h0 = *(const float4*)(hb + (size_t)i0 * COUT);
    const float4 h4 = *(const float4*)(hb + (size_t)i1 * COUT);
    const float4 h8 = *(const float4*)(hb + (size_t)i2 * COUT);

    const size_t oi = (size_t)row * COUT + c;
    float4 yv = *(const float4*)&out[oi];
    float4 r;
    r.x = fmaxf(fmaf(yv.x, sc2.x, sh2.x), 0.f)
        + w0 * fmaxf(fmaf(h0.x, sc1.x, sh1.x), 0.f)
        + w1 * fmaxf(fmaf(h4.x, sc1.x, sh1.x), 0.f)
        + w2 * fmaxf(fmaf(h8.x, sc1.x, sh1.x), 0.f);
    r.y = fmaxf(fmaf(yv.y, sc2.y, sh2.y), 0.f)
        + w0 * fmaxf(fmaf(h0.y, sc1.y, sh1.y), 0.f)
        + w1 * fmaxf(fmaf(h4.y, sc1.y, sh1.y), 0.f)
        + w2 * fmaxf(fmaf(h8.y, sc1.y, sh1.y), 0.f);
    r.z = fmaxf(fmaf(yv.z, sc2.z, sh2.z), 0.f)
        + w0 * fmaxf(fmaf(h0.z, sc1.z, sh1.z), 0.f)
        + w1 * fmaxf(fmaf(h4.z, sc1.z, sh1.z), 0.f)
        + w2 * fmaxf(fmaf(h8.z, sc1.z, sh1.z), 0.f);
    r.w = fmaxf(fmaf(yv.w, sc2.w, sh2.w), 0.f)
        + w0 * fmaxf(fmaf(h0.w, sc1.w, sh1.w), 0.f)
        + w1 * fmaxf(fmaf(h4.w, sc1.w, sh1.w), 0.f)
        + w2 * fmaxf(fmaf(h8.w, sc1.w, sh1.w), 0.f);
    *(float4*)&out[oi] = r;
}

// ---------------------------------------------------------------------------
extern "C" void kernel_launch(void* const* d_in, const int* in_sizes, int n_in,
                              void* d_out, int out_size, void* d_ws, size_t ws_size,
                              hipStream_t stream) {
    const float* x1       = (const float*)d_in[0];
    const float* p1       = (const float*)d_in[1];
    const float* x2       = (const float*)d_in[2];
    const float* p2       = (const float*)d_in[3];
    const float* W_up     = (const float*)d_in[4];
    const float* gamma_up = (const float*)d_in[5];
    const float* beta_up  = (const float*)d_in[6];
    const float* W_lat    = (const float*)d_in[7];
    const float* gamma_lat= (const float*)d_in[8];
    const float* beta_lat = (const float*)d_in[9];
    float* out = (float*)d_out;

    // workspace layout (~35.3 MB); h1 and stats adjacent -> one memset
    char* w = (char*)d_ws;
    unsigned short* x1h = (unsigned short*)(w);                          // 4 MB
    unsigned short* x1l = (unsigned short*)(w + (4u<<20));               // 4 MB
    unsigned short* x2h = (unsigned short*)(w + (8u<<20));               // 8 MB
    unsigned short* x2l = (unsigned short*)(w + (16u<<20));              // 8 MB
    unsigned short* wuh = (unsigned short*)(w + (24u<<20));              // 256 KB
    unsigned short* wul = (unsigned short*)(w + (24u<<20) + (256u<<10));
    unsigned short* wlh = (unsigned short*)(w + (24u<<20) + (512u<<10)); // 128 KB
    unsigned short* wll = (unsigned short*)(w + (24u<<20) + (640u<<10));
    float*  h1    = (float*)(w + (25u<<20));                             // 4 MB
    float*  stats = (float*)(w + (29u<<20));                             // 4 KB
    float2* part  = (float2*)(w + (29u<<20) + (16u<<10));                // 6.3 MB

    // zero h1 (splitK accumulator) + stats in one fill
    hipMemsetAsync(h1, 0, (4u << 20) + 4096, stream);

    // K1: pre-split (3168 blocks) + three_nn partials (1024 blocks)
    prep_fused<<<3168 + 1024, 256, 0, stream>>>(x1, x2, W_up, W_lat, p1, p2,
                                                x1h, x1l, x2h, x2l,
                                                wuh, wul, wlh, wll, part);

    // K2: both GEMMs, 2048 blocks
    gemm_fused<<<2048, 256, 0, stream>>>(x1h, x1l, wuh, wul,
                                         x2h, x2l, wlh, wll, h1, out, stats);

    // BN1 stats from h1
    colsum256<<<256, 256, 0, stream>>>(h1, ROWS1 / 256, stats);

    // K4: merge + gather-interp (+BN1+ReLU) + BN2 + ReLU + add
    final_combine<<<ROWS2 / 4, 256, 0, stream>>>(h1, stats, gamma_up, beta_up,
                                                 gamma_lat, beta_lat, part, out);

    // p2 passthrough -> second output
    hipMemcpyAsync(out + (size_t)ROWS2 * COUT, p2,
                   (size_t)ROWS2 * 3 * sizeof(float),
                   hipMemcpyDeviceToDevice, stream);
}

// Round 9
// 178.303 us; speedup vs baseline: 1.3147x; 1.0779x over previous
//
#include <hip/hip_runtime.h>

// Problem constants (fixed by setup_inputs)
#define BATCH 2
#define NPTS  2048
#define MPTS  8192
#define CIN1  512
#define CIN2  256
#define COUT  256
#define ROWS1 (BATCH*NPTS)   // 4096
#define ROWS2 (BATCH*MPTS)   // 16384
#define BN_EPS 1e-5f
#define NN_EPS 1e-8f

#define NCHUNK 16
#define CHUNK  (NPTS / NCHUNK)   // 128
#define HCHUNK (CHUNK / 2)       // 64

typedef __attribute__((ext_vector_type(8))) short  bf16x8;
typedef __attribute__((ext_vector_type(4))) float  f32x4;

#define AS1 __attribute__((address_space(1)))
#define AS3 __attribute__((address_space(3)))

__device__ __forceinline__ unsigned short bf16_rne(float x) {
    unsigned u = __float_as_uint(x);
    u += 0x7FFFu + ((u >> 16) & 1u);
    return (unsigned short)(u >> 16);
}
__device__ __forceinline__ void gload16(const void* g, void* l) {
    __builtin_amdgcn_global_load_lds((const AS1 unsigned int*)g,
                                     (AS3 unsigned int*)l, 16, 0, 0);
}

// ---------------------------------------------------------------------------
// K1: fused {f32 -> bf16(hi only) swizzled tile images} + {three_nn partials}
//     + {stats zero}.
// Split tile = 64 rows x 32 k, 4096 B; element (row, k-octet lg) at byte
// (row*64 + lg*16) ^ ((row&7)<<4)  [G4 XOR swizzle baked into the image].
// part layout [chunk][row]: per-block writes are lane-contiguous (coalesced).
// ---------------------------------------------------------------------------
__global__ __launch_bounds__(256)
void prep_fused(const float* __restrict__ x1, const float* __restrict__ x2,
                const float* __restrict__ wu, const float* __restrict__ wl,
                const float* __restrict__ p1, const float* __restrict__ p2,
                unsigned short* __restrict__ x1h, unsigned short* __restrict__ x2h,
                unsigned short* __restrict__ wuh, unsigned short* __restrict__ wlh,
                float2* __restrict__ part, float* __restrict__ stats) {
    const int bid = blockIdx.x;
    const int t = threadIdx.x;
    if (bid < 3168) {
        // ---------------- bf16-hi split ----------------
        const float* src; unsigned short* dh; int K, tile;
        if (bid < 1024)      { src = x1; dh = x1h; K = CIN1; tile = bid; }
        else if (bid < 3072) { src = x2; dh = x2h; K = CIN2; tile = bid - 1024; }
        else if (bid < 3136) { src = wu; dh = wuh; K = CIN1; tile = bid - 3072; }
        else                 { src = wl; dh = wlh; K = CIN2; tile = bid - 3136; }
        const int ktiles = K / 32;
        const int rt = tile / ktiles, kt = tile - rt * ktiles;
        const int row = t >> 2, lg = t & 3;
        const float* s = src + (size_t)(rt * 64 + row) * K + kt * 32 + lg * 8;
        const float4 v0 = *(const float4*)s;
        const float4 v1 = *(const float4*)(s + 4);
        const float vv[8] = {v0.x, v0.y, v0.z, v0.w, v1.x, v1.y, v1.z, v1.w};
        bf16x8 h;
        #pragma unroll
        for (int i = 0; i < 8; ++i) h[i] = (short)bf16_rne(vv[i]);
        const unsigned off = ((unsigned)(row * 64 + lg * 16)) ^ ((unsigned)((row & 7) << 4));
        *(bf16x8*)((char*)dh + (size_t)tile * 4096 + off) = h;
    } else if (bid < 4192) {
        // ---------------- three_nn partials (2 independent half-chains) ----
        __shared__ float4 pts[CHUNK];
        const int q = bid - 3168;
        const int b = q >> 9;
        const int r = q & 511;
        const int ck = r >> 5;             // chunk 0..15
        const int mblk = r & 31;           // query block 0..31
        const int n0 = ck * CHUNK;
        if (t < CHUNK) {
            const float* P1 = p1 + ((size_t)b * NPTS + n0) * 3;
            float x = P1[t * 3 + 0], y = P1[t * 3 + 1], z = P1[t * 3 + 2];
            pts[t] = make_float4(x, y, z, x * x + y * y + z * z);
        }
        __syncthreads();
        const int m = mblk * 256 + t;
        const int row = b * MPTS + m;
        const float* qp = p2 + (size_t)row * 3;
        const float qx = qp[0], qy = qp[1], qz = qp[2];
        const float s2 = qx * qx + qy * qy + qz * qz;
        float dA0 = 1e30f, dA1 = 1e30f, dA2 = 1e30f;
        int   iA0 = 0,     iA1 = 0,     iA2 = 0;
        float dB0 = 1e30f, dB1 = 1e30f, dB2 = 1e30f;
        int   iB0 = 0,     iB1 = 0,     iB2 = 0;
        #pragma unroll 4
        for (int n = 0; n < HCHUNK; ++n) {
            float4 pA = pts[n];
            float4 pB = pts[n + HCHUNK];
            float dA = s2 + pA.w - 2.0f * (pA.x * qx + pA.y * qy + pA.z * qz);
            float dB = s2 + pB.w - 2.0f * (pB.x * qx + pB.y * qy + pB.z * qz);
            if (dA < dA2) {
                if (dA < dA1) {
                    dA2 = dA1; iA2 = iA1;
                    if (dA < dA0) { dA1 = dA0; iA1 = iA0; dA0 = dA; iA0 = n0 + n; }
                    else          { dA1 = dA; iA1 = n0 + n; }
                } else { dA2 = dA; iA2 = n0 + n; }
            }
            if (dB < dB2) {
                if (dB < dB1) {
                    dB2 = dB1; iB2 = iB1;
                    if (dB < dB0) { dB1 = dB0; iB1 = iB0; dB0 = dB; iB0 = n0 + HCHUNK + n; }
                    else          { dB1 = dB; iB1 = n0 + HCHUNK + n; }
                } else { dB2 = dB; iB2 = n0 + HCHUNK + n; }
            }
        }
        // merge B into A: strict '<' keeps A (lower indices) on ties == reference
        #define INS3(d, i) \
            if ((d) < dA2) { \
                if ((d) < dA1) { \
                    dA2 = dA1; iA2 = iA1; \
                    if ((d) < dA0) { dA1 = dA0; iA1 = iA0; dA0 = (d); iA0 = (i); } \
                    else           { dA1 = (d); iA1 = (i); } \
                } else { dA2 = (d); iA2 = (i); } \
            }
        INS3(dB0, iB0); INS3(dB1, iB1); INS3(dB2, iB2);
        #undef INS3
        float2* o = part + ((size_t)ck * ROWS2 + row) * 3;
        o[0] = make_float2(dA0, __int_as_float(iA0));
        o[1] = make_float2(dA1, __int_as_float(iA1));
        o[2] = make_float2(dA2, __int_as_float(iA2));
    } else {
        // ---------------- zero stats (1024 floats) ----------------
        ((float4*)stats)[t] = (float4){0.f, 0.f, 0.f, 0.f};
    }
}

// ---------------------------------------------------------------------------
// GEMM body: bf16(hi) MFMA on pre-swizzled tile images.
// 3-buffer LDS pipeline, counted vmcnt(2): stage t+1 stays in flight across
// the barrier; stage t+2 issued right after it. One barrier per k-tile.
// Waves 0,1 stage A halves; waves 2,3 stage B halves (2 x 1KB DMA each).
// Epilogue: acc -> LDS transpose (union with stage bufs) -> float4 stores,
// + fused per-channel sum/sumsq atomics (both GEMMs full-K now).
// ---------------------------------------------------------------------------
union GemmLds {
    unsigned char stage[3][2][4096];   // [stage%3][A,B]  24 KB
    float Ct[64][68];                  // 17.4 KB epilogue transpose
};

template<int KTILES>
__device__ __forceinline__ void gemm_body(
        const unsigned short* __restrict__ A_img, const unsigned short* __restrict__ B_img,
        float* __restrict__ C, float* __restrict__ stats,
        int bx, int by, GemmLds& S, float red[64][8]) {
    const int tid = threadIdx.x;
    const int lane = tid & 63, wid = tid >> 6;
    const int m0 = by * 64, o0 = bx * 64;
    const int wy = wid >> 1, wx = wid & 1;
    const int lr = lane & 15, lg = lane >> 4;

    const int mat = wid >> 1;            // 0: A, 1: B
    const int half = wid & 1;
    const unsigned short* src = mat ? B_img : A_img;
    const size_t base = ((size_t)(mat ? bx : by) * KTILES) * 2048 + half * 1024;

    f32x4 acc[2][2];
    #pragma unroll
    for (int i = 0; i < 2; ++i)
        #pragma unroll
        for (int j = 0; j < 2; ++j)
            acc[i][j] = (f32x4){0.f, 0.f, 0.f, 0.f};

    auto STAGE = [&](int buf, int tt) {
        const unsigned short* s = src + base + (size_t)tt * 2048;
        char* l = (char*)&S.stage[buf][mat][half * 2048];
        gload16(s + (size_t)lane * 8, l);
        gload16(s + 512 + (size_t)lane * 8, l + 1024);
    };
    auto FOFF = [&](int row) -> int {
        return (row * 64 + lg * 16) ^ ((row & 7) << 4);
    };

    STAGE(0, 0);
    STAGE(1, 1);

    for (int t = 0; t < KTILES; ++t) {
        if (t + 1 < KTILES) asm volatile("s_waitcnt vmcnt(2)" ::: "memory");
        else                asm volatile("s_waitcnt vmcnt(0)" ::: "memory");
        __builtin_amdgcn_s_barrier();
        __builtin_amdgcn_sched_barrier(0);
        if (t + 2 < KTILES) STAGE((t + 2) % 3, t + 2);

        const int cb = t % 3;
        const char* LA = (const char*)&S.stage[cb][0][0];
        const char* LB = (const char*)&S.stage[cb][1][0];

        bf16x8 fa[2], fb[2];
        #pragma unroll
        for (int i = 0; i < 2; ++i)
            fa[i] = *(const bf16x8*)(LA + FOFF(wy * 32 + i * 16 + lr));
        #pragma unroll
        for (int j = 0; j < 2; ++j)
            fb[j] = *(const bf16x8*)(LB + FOFF(wx * 32 + j * 16 + lr));
        #pragma unroll
        for (int i = 0; i < 2; ++i)
            #pragma unroll
            for (int j = 0; j < 2; ++j)
                acc[i][j] = __builtin_amdgcn_mfma_f32_16x16x32_bf16(fa[i], fb[j], acc[i][j], 0, 0, 0);
    }

    // ---- epilogue: acc -> LDS transpose -> coalesced float4 stores ----
    __syncthreads();   // stage bufs now reusable as Ct
    #pragma unroll
    for (int i = 0; i < 2; ++i)
        #pragma unroll
        for (int j = 0; j < 2; ++j) {
            const int col = wx * 32 + j * 16 + lr;
            const int rbase = wy * 32 + i * 16 + lg * 4;
            #pragma unroll
            for (int r = 0; r < 4; ++r)
                S.Ct[rbase + r][col] = acc[i][j][r];
        }
    __syncthreads();
    {
        const int cr = tid >> 4;          // 0..15
        const int cc = (tid & 15) * 4;    // 0..60
        #pragma unroll
        for (int q = 0; q < 4; ++q) {
            const int row = cr + q * 16;
            *(float4*)&C[(size_t)(m0 + row) * COUT + o0 + cc] =
                *(const float4*)&S.Ct[row][cc];
        }
    }
    // ---- fused BN stats from the transposed tile ----
    {
        const int col = tid & 63, rq = tid >> 6;   // 4 threads per column
        float s = 0.f, q2 = 0.f;
        #pragma unroll
        for (int r = 0; r < 16; ++r) {
            float v = S.Ct[rq * 16 + r][col];
            s += v;
            q2 = fmaf(v, v, q2);
        }
        red[col][rq] = s;
        red[col][4 + rq] = q2;
    }
    __syncthreads();
    if (tid < 64) {
        float ss = red[tid][0] + red[tid][1] + red[tid][2] + red[tid][3];
        float qq = red[tid][4] + red[tid][5] + red[tid][6] + red[tid][7];
        atomicAdd(&stats[o0 + tid], ss);
        atomicAdd(&stats[COUT + o0 + tid], qq);
    }
}

// K2: both GEMMs in one 1280-block launch (all blocks co-resident at 5/CU).
// blocks [0,256): gemm1 (up, K=512, fused BN1 stats) -> h1
// blocks [256,1280): gemm2 (lateral, K=256, fused BN2 stats) -> out
__global__ __launch_bounds__(256)
void gemm_fused(const unsigned short* __restrict__ x1h, const unsigned short* __restrict__ wuh,
                const unsigned short* __restrict__ x2h, const unsigned short* __restrict__ wlh,
                float* __restrict__ h1, float* __restrict__ out, float* __restrict__ stats) {
    __shared__ GemmLds S;
    __shared__ float red[64][8];
    const int bid = blockIdx.x;
    if (bid < 256) {
        gemm_body<CIN1/32>(x1h, wuh, h1, stats, bid & 3, bid >> 2, S, red);
    } else {
        const int q = bid - 256;
        gemm_body<CIN2/32>(x2h, wlh, out, stats + 512, q & 3, q >> 2, S, red);
    }
}

// ---------------------------------------------------------------------------
// Final: wave-uniform merge of NCHUNK top-3 partials + gather-interp
// (+BN1+ReLU) + BN2 + ReLU + add, in place on d_out.
// part layout [chunk][row]: 16 broadcast reads of 24 B per row.
// ---------------------------------------------------------------------------
__global__ __launch_bounds__(256)
void final_combine(const float* __restrict__ h1, const float* __restrict__ stats,
                   const float* __restrict__ g1, const float* __restrict__ b1,
                   const float* __restrict__ g2, const float* __restrict__ b2,
                   const float2* __restrict__ part, float* __restrict__ out) {
    const int t = threadIdx.x;
    const int row = blockIdx.x * 4 + (t >> 6);
    const int c = (t & 63) * 4;
    const int b = row >> 13;

    float d0 = 1e30f, d1 = 1e30f, d2 = 1e30f;
    int   i0 = 0,     i1 = 0,     i2 = 0;
    #pragma unroll
    for (int ck = 0; ck < NCHUNK; ++ck) {
        const float2* pe = part + ((size_t)ck * ROWS2 + row) * 3;
        #pragma unroll
        for (int h = 0; h < 3; ++h) {
            float2 v = pe[h];
            float d = v.x;
            int   i = __float_as_int(v.y);
            if (d < d2) {
                if (d < d1) {
                    d2 = d1; i2 = i1;
                    if (d < d0) { d1 = d0; i1 = i0; d0 = d; i0 = i; }
                    else        { d1 = d;  i1 = i; }
                } else { d2 = d; i2 = i; }
            }
        }
    }
    const float r0 = 1.0f / (d0 + NN_EPS);
    const float r1 = 1.0f / (d1 + NN_EPS);
    const float r2 = 1.0f / (d2 + NN_EPS);
    const float irs = 1.0f / (r0 + r1 + r2);
    const float w0 = r0 * irs, w1 = r1 * irs, w2 = r2 * irs;

    const float4 sum1 = *(const float4*)&stats[c];
    const float4 sq1  = *(const float4*)&stats[COUT + c];
    const float4 sum2 = *(const float4*)&stats[512 + c];
    const float4 sq2  = *(const float4*)&stats[768 + c];
    const float4 gg1  = *(const float4*)&g1[c];
    const float4 bb1  = *(const float4*)&b1[c];
    const float4 gg2  = *(const float4*)&g2[c];
    const float4 bb2  = *(const float4*)&b2[c];

    const float inv1 = 1.0f / (float)ROWS1, inv2 = 1.0f / (float)ROWS2;
    float4 sc1, sh1, sc2, sh2;
    {
        float m, v;
        m = sum1.x*inv1; v = fmaf(-m,m,sq1.x*inv1); sc1.x = gg1.x/sqrtf(v+BN_EPS); sh1.x = fmaf(-m,sc1.x,bb1.x);
        m = sum1.y*inv1; v = fmaf(-m,m,sq1.y*inv1); sc1.y = gg1.y/sqrtf(v+BN_EPS); sh1.y = fmaf(-m,sc1.y,bb1.y);
        m = sum1.z*inv1; v = fmaf(-m,m,sq1.z*inv1); sc1.z = gg1.z/sqrtf(v+BN_EPS); sh1.z = fmaf(-m,sc1.z,bb1.z);
        m = sum1.w*inv1; v = fmaf(-m,m,sq1.w*inv1); sc1.w = gg1.w/sqrtf(v+BN_EPS); sh1.w = fmaf(-m,sc1.w,bb1.w);
        m = sum2.x*inv2; v = fmaf(-m,m,sq2.x*inv2); sc2.x = gg2.x/sqrtf(v+BN_EPS); sh2.x = fmaf(-m,sc2.x,bb2.x);
        m = sum2.y*inv2; v = fmaf(-m,m,sq2.y*inv2); sc2.y = gg2.y/sqrtf(v+BN_EPS); sh2.y = fmaf(-m,sc2.y,bb2.y);
        m = sum2.z*inv2; v = fmaf(-m,m,sq2.z*inv2); sc2.z = gg2.z/sqrtf(v+BN_EPS); sh2.z = fmaf(-m,sc2.z,bb2.z);
        m = sum2.w*inv2; v = fmaf(-m,m,sq2.w*inv2); sc2.w = gg2.w/sqrtf(v+BN_EPS); sh2.w = fmaf(-m,sc2.w,bb2.w);
    }

    const float* hb = h1 + (size_t)b * NPTS * COUT + c;
    const float4 h0 = *(const float4*)(hb + (size_t)i0 * COUT);
    const float4 h4 = *(const float4*)(hb + (size_t)i1 * COUT);
    const float4 h8 = *(const float4*)(hb + (size_t)i2 * COUT);

    const size_t oi = (size_t)row * COUT + c;
    float4 yv = *(const float4*)&out[oi];
    float4 r;
    r.x = fmaxf(fmaf(yv.x, sc2.x, sh2.x), 0.f)
        + w0 * fmaxf(fmaf(h0.x, sc1.x, sh1.x), 0.f)
        + w1 * fmaxf(fmaf(h4.x, sc1.x, sh1.x), 0.f)
        + w2 * fmaxf(fmaf(h8.x, sc1.x, sh1.x), 0.f);
    r.y = fmaxf(fmaf(yv.y, sc2.y, sh2.y), 0.f)
        + w0 * fmaxf(fmaf(h0.y, sc1.y, sh1.y), 0.f)
        + w1 * fmaxf(fmaf(h4.y, sc1.y, sh1.y), 0.f)
        + w2 * fmaxf(fmaf(h8.y, sc1.y, sh1.y), 0.f);
    r.z = fmaxf(fmaf(yv.z, sc2.z, sh2.z), 0.f)
        + w0 * fmaxf(fmaf(h0.z, sc1.z, sh1.z), 0.f)
        + w1 * fmaxf(fmaf(h4.z, sc1.z, sh1.z), 0.f)
        + w2 * fmaxf(fmaf(h8.z, sc1.z, sh1.z), 0.f);
    r.w = fmaxf(fmaf(yv.w, sc2.w, sh2.w), 0.f)
        + w0 * fmaxf(fmaf(h0.w, sc1.w, sh1.w), 0.f)
        + w1 * fmaxf(fmaf(h4.w, sc1.w, sh1.w), 0.f)
        + w2 * fmaxf(fmaf(h8.w, sc1.w, sh1.w), 0.f);
    *(float4*)&out[oi] = r;
}

// ---------------------------------------------------------------------------
extern "C" void kernel_launch(void* const* d_in, const int* in_sizes, int n_in,
                              void* d_out, int out_size, void* d_ws, size_t ws_size,
                              hipStream_t stream) {
    const float* x1       = (const float*)d_in[0];
    const float* p1       = (const float*)d_in[1];
    const float* x2       = (const float*)d_in[2];
    const float* p2       = (const float*)d_in[3];
    const float* W_up     = (const float*)d_in[4];
    const float* gamma_up = (const float*)d_in[5];
    const float* beta_up  = (const float*)d_in[6];
    const float* W_lat    = (const float*)d_in[7];
    const float* gamma_lat= (const float*)d_in[8];
    const float* beta_lat = (const float*)d_in[9];
    float* out = (float*)d_out;

    // workspace layout (~24 MB)
    char* w = (char*)d_ws;
    unsigned short* x1h = (unsigned short*)(w);                           // 4 MB
    unsigned short* x2h = (unsigned short*)(w + (4u<<20));                // 8 MB
    unsigned short* wuh = (unsigned short*)(w + (12u<<20));               // 256 KB
    unsigned short* wlh = (unsigned short*)(w + (12u<<20) + (256u<<10));  // 128 KB
    float*  h1    = (float*)(w + (13u<<20));                              // 4 MB
    float*  stats = (float*)(w + (17u<<20));                              // 4 KB
    float2* part  = (float2*)(w + (17u<<20) + (16u<<10));                 // 6.3 MB

    // K1: split (3168) + three_nn partials (1024) + stats zero (1)
    prep_fused<<<4193, 256, 0, stream>>>(x1, x2, W_up, W_lat, p1, p2,
                                         x1h, x2h, wuh, wlh, part, stats);

    // K2: both GEMMs, 1280 blocks, full-K, fused BN stats
    gemm_fused<<<1280, 256, 0, stream>>>(x1h, wuh, x2h, wlh, h1, out, stats);

    // K3: merge + gather-interp (+BN1+ReLU) + BN2 + ReLU + add
    final_combine<<<ROWS2 / 4, 256, 0, stream>>>(h1, stats, gamma_up, beta_up,
                                                 gamma_lat, beta_lat, part, out);

    // p2 passthrough -> second output
    hipMemcpyAsync(out + (size_t)ROWS2 * COUT, p2,
                   (size_t)ROWS2 * 3 * sizeof(float),
                   hipMemcpyDeviceToDevice, stream);
}

// Round 10
// 175.012 us; speedup vs baseline: 1.3394x; 1.0188x over previous
//
#include <hip/hip_runtime.h>

// Problem constants (fixed by setup_inputs)
#define BATCH 2
#define NPTS  2048
#define MPTS  8192
#define CIN1  512
#define CIN2  256
#define COUT  256
#define ROWS1 (BATCH*NPTS)   // 4096
#define ROWS2 (BATCH*MPTS)   // 16384
#define BN_EPS 1e-5f
#define NN_EPS 1e-8f

#define NCHUNK 16
#define CHUNK  (NPTS / NCHUNK)   // 128

typedef __attribute__((ext_vector_type(8))) short  bf16x8;
typedef __attribute__((ext_vector_type(4))) float  f32x4;

#define AS1 __attribute__((address_space(1)))
#define AS3 __attribute__((address_space(3)))

__device__ __forceinline__ unsigned short bf16_rne(float x) {
    unsigned u = __float_as_uint(x);
    u += 0x7FFFu + ((u >> 16) & 1u);
    return (unsigned short)(u >> 16);
}
__device__ __forceinline__ void gload16(const void* g, void* l) {
    __builtin_amdgcn_global_load_lds((const AS1 unsigned int*)g,
                                     (AS3 unsigned int*)l, 16, 0, 0);
}

// ---------------------------------------------------------------------------
// K1a: f32 -> bf16(hi) swizzled tile images.  Tile = 64 rows x 32 k, 4096 B;
// element (row, k-octet lg) at byte (row*64+lg*16) ^ ((row&7)<<4).
// ---------------------------------------------------------------------------
__global__ __launch_bounds__(256)
void split_pre(const float* __restrict__ x1, const float* __restrict__ x2,
               const float* __restrict__ wu, const float* __restrict__ wl,
               unsigned short* __restrict__ x1h, unsigned short* __restrict__ x2h,
               unsigned short* __restrict__ wuh, unsigned short* __restrict__ wlh) {
    const int bid = blockIdx.x;
    const int t = threadIdx.x;
    const float* src; unsigned short* dh; int K, tile;
    if (bid < 1024)      { src = x1; dh = x1h; K = CIN1; tile = bid; }
    else if (bid < 3072) { src = x2; dh = x2h; K = CIN2; tile = bid - 1024; }
    else if (bid < 3136) { src = wu; dh = wuh; K = CIN1; tile = bid - 3072; }
    else                 { src = wl; dh = wlh; K = CIN2; tile = bid - 3136; }
    const int ktiles = K / 32;
    const int rt = tile / ktiles, kt = tile - rt * ktiles;
    const int row = t >> 2, lg = t & 3;
    const float* s = src + (size_t)(rt * 64 + row) * K + kt * 32 + lg * 8;
    const float4 v0 = *(const float4*)s;
    const float4 v1 = *(const float4*)(s + 4);
    const float vv[8] = {v0.x, v0.y, v0.z, v0.w, v1.x, v1.y, v1.z, v1.w};
    bf16x8 h;
    #pragma unroll
    for (int i = 0; i < 8; ++i) h[i] = (short)bf16_rne(vv[i]);
    const unsigned off = ((unsigned)(row * 64 + lg * 16)) ^ ((unsigned)((row & 7) << 4));
    *(bf16x8*)((char*)dh + (size_t)tile * 4096 + off) = h;
}

// ---------------------------------------------------------------------------
// K1b: three_nn partials.  Batched: 4 LDS float4 loads + 4 independent dist
// computations per iteration, then 4 in-order inserts (strict '<' keeps the
// earliest index on ties == reference tie order).
// part layout [chunk][row]: per-block writes lane-contiguous (coalesced).
// ---------------------------------------------------------------------------
__global__ __launch_bounds__(256)
void nn_part(const float* __restrict__ p1, const float* __restrict__ p2,
             float2* __restrict__ part) {
    __shared__ float4 pts[CHUNK];
    const int b = blockIdx.z;
    const int ck = blockIdx.y;
    const int mblk = blockIdx.x;
    const int t = threadIdx.x;
    const int n0 = ck * CHUNK;
    if (t < CHUNK) {
        const float* P1 = p1 + ((size_t)b * NPTS + n0) * 3;
        float x = P1[t * 3 + 0], y = P1[t * 3 + 1], z = P1[t * 3 + 2];
        pts[t] = make_float4(x, y, z, x * x + y * y + z * z);
    }
    __syncthreads();
    const int m = mblk * 256 + t;
    const int row = b * MPTS + m;
    const float* qp = p2 + (size_t)row * 3;
    const float qx = qp[0], qy = qp[1], qz = qp[2];
    const float s2 = qx * qx + qy * qy + qz * qz;
    float d0 = 1e30f, d1 = 1e30f, d2 = 1e30f;
    int   i0 = 0,     i1 = 0,     i2 = 0;
    #define INS(d, i) \
        if ((d) < d2) { \
            if ((d) < d1) { \
                d2 = d1; i2 = i1; \
                if ((d) < d0) { d1 = d0; i1 = i0; d0 = (d); i0 = (i); } \
                else          { d1 = (d); i1 = (i); } \
            } else { d2 = (d); i2 = (i); } \
        }
    for (int n = 0; n < CHUNK; n += 4) {
        float4 pa = pts[n + 0];
        float4 pb = pts[n + 1];
        float4 pc = pts[n + 2];
        float4 pd = pts[n + 3];
        float da = s2 + pa.w - 2.0f * (pa.x * qx + pa.y * qy + pa.z * qz);
        float db = s2 + pb.w - 2.0f * (pb.x * qx + pb.y * qy + pb.z * qz);
        float dc = s2 + pc.w - 2.0f * (pc.x * qx + pc.y * qy + pc.z * qz);
        float dd = s2 + pd.w - 2.0f * (pd.x * qx + pd.y * qy + pd.z * qz);
        INS(da, n0 + n + 0);
        INS(db, n0 + n + 1);
        INS(dc, n0 + n + 2);
        INS(dd, n0 + n + 3);
    }
    #undef INS
    float2* o = part + ((size_t)ck * ROWS2 + row) * 3;
    o[0] = make_float2(d0, __int_as_float(i0));
    o[1] = make_float2(d1, __int_as_float(i1));
    o[2] = make_float2(d2, __int_as_float(i2));
}

// ---------------------------------------------------------------------------
// GEMM body: bf16(hi) MFMA on pre-swizzled tile images.  3-buffer pipeline,
// counted vmcnt(2).  Epilogue: LDS transpose -> float4 stores + fused stats.
// ---------------------------------------------------------------------------
union GemmLds {
    unsigned char stage[3][2][4096];   // [stage%3][A,B]  24 KB
    float Ct[64][68];                  // 17.4 KB epilogue transpose
};

template<int KTILES>
__device__ __forceinline__ void gemm_body(
        const unsigned short* __restrict__ A_img, const unsigned short* __restrict__ B_img,
        float* __restrict__ C, float* __restrict__ stats,
        int bx, int by, GemmLds& S, float red[64][8]) {
    const int tid = threadIdx.x;
    const int lane = tid & 63, wid = tid >> 6;
    const int m0 = by * 64, o0 = bx * 64;
    const int wy = wid >> 1, wx = wid & 1;
    const int lr = lane & 15, lg = lane >> 4;

    const int mat = wid >> 1;            // 0: A, 1: B
    const int half = wid & 1;
    const unsigned short* src = mat ? B_img : A_img;
    const size_t base = ((size_t)(mat ? bx : by) * KTILES) * 2048 + half * 1024;

    f32x4 acc[2][2];
    #pragma unroll
    for (int i = 0; i < 2; ++i)
        #pragma unroll
        for (int j = 0; j < 2; ++j)
            acc[i][j] = (f32x4){0.f, 0.f, 0.f, 0.f};

    auto STAGE = [&](int buf, int tt) {
        const unsigned short* s = src + base + (size_t)tt * 2048;
        char* l = (char*)&S.stage[buf][mat][half * 2048];
        gload16(s + (size_t)lane * 8, l);
        gload16(s + 512 + (size_t)lane * 8, l + 1024);
    };
    auto FOFF = [&](int row) -> int {
        return (row * 64 + lg * 16) ^ ((row & 7) << 4);
    };

    STAGE(0, 0);
    STAGE(1, 1);

    for (int t = 0; t < KTILES; ++t) {
        if (t + 1 < KTILES) asm volatile("s_waitcnt vmcnt(2)" ::: "memory");
        else                asm volatile("s_waitcnt vmcnt(0)" ::: "memory");
        __builtin_amdgcn_s_barrier();
        __builtin_amdgcn_sched_barrier(0);
        if (t + 2 < KTILES) STAGE((t + 2) % 3, t + 2);

        const int cb = t % 3;
        const char* LA = (const char*)&S.stage[cb][0][0];
        const char* LB = (const char*)&S.stage[cb][1][0];

        bf16x8 fa[2], fb[2];
        #pragma unroll
        for (int i = 0; i < 2; ++i)
            fa[i] = *(const bf16x8*)(LA + FOFF(wy * 32 + i * 16 + lr));
        #pragma unroll
        for (int j = 0; j < 2; ++j)
            fb[j] = *(const bf16x8*)(LB + FOFF(wx * 32 + j * 16 + lr));
        #pragma unroll
        for (int i = 0; i < 2; ++i)
            #pragma unroll
            for (int j = 0; j < 2; ++j)
                acc[i][j] = __builtin_amdgcn_mfma_f32_16x16x32_bf16(fa[i], fb[j], acc[i][j], 0, 0, 0);
    }

    // ---- epilogue: acc -> LDS transpose -> coalesced float4 stores ----
    __syncthreads();
    #pragma unroll
    for (int i = 0; i < 2; ++i)
        #pragma unroll
        for (int j = 0; j < 2; ++j) {
            const int col = wx * 32 + j * 16 + lr;
            const int rbase = wy * 32 + i * 16 + lg * 4;
            #pragma unroll
            for (int r = 0; r < 4; ++r)
                S.Ct[rbase + r][col] = acc[i][j][r];
        }
    __syncthreads();
    {
        const int cr = tid >> 4;
        const int cc = (tid & 15) * 4;
        #pragma unroll
        for (int q = 0; q < 4; ++q) {
            const int row = cr + q * 16;
            *(float4*)&C[(size_t)(m0 + row) * COUT + o0 + cc] =
                *(const float4*)&S.Ct[row][cc];
        }
    }
    {
        const int col = tid & 63, rq = tid >> 6;
        float s = 0.f, q2 = 0.f;
        #pragma unroll
        for (int r = 0; r < 16; ++r) {
            float v = S.Ct[rq * 16 + r][col];
            s += v;
            q2 = fmaf(v, v, q2);
        }
        red[col][rq] = s;
        red[col][4 + rq] = q2;
    }
    __syncthreads();
    if (tid < 64) {
        float ss = red[tid][0] + red[tid][1] + red[tid][2] + red[tid][3];
        float qq = red[tid][4] + red[tid][5] + red[tid][6] + red[tid][7];
        atomicAdd(&stats[o0 + tid], ss);
        atomicAdd(&stats[COUT + o0 + tid], qq);
    }
}

// K2: both GEMMs in one 1280-block launch.
__global__ __launch_bounds__(256)
void gemm_fused(const unsigned short* __restrict__ x1h, const unsigned short* __restrict__ wuh,
                const unsigned short* __restrict__ x2h, const unsigned short* __restrict__ wlh,
                float* __restrict__ h1, float* __restrict__ out, float* __restrict__ stats) {
    __shared__ GemmLds S;
    __shared__ float red[64][8];
    const int bid = blockIdx.x;
    if (bid < 256) {
        gemm_body<CIN1/32>(x1h, wuh, h1, stats, bid & 3, bid >> 2, S, red);
    } else {
        const int q = bid - 256;
        gemm_body<CIN2/32>(x2h, wlh, out, stats + 512, q & 3, q >> 2, S, red);
    }
}

// ---------------------------------------------------------------------------
// K3: wave-uniform merge of NCHUNK top-3 partials + gather-interp
// (+BN1+ReLU) + BN2 + ReLU + add, in place on d_out.
// ---------------------------------------------------------------------------
__global__ __launch_bounds__(256)
void final_combine(const float* __restrict__ h1, const float* __restrict__ stats,
                   const float* __restrict__ g1, const float* __restrict__ b1,
                   const float* __restrict__ g2, const float* __restrict__ b2,
                   const float2* __restrict__ part, float* __restrict__ out) {
    const int t = threadIdx.x;
    const int row = blockIdx.x * 4 + (t >> 6);
    const int c = (t & 63) * 4;
    const int b = row >> 13;

    float d0 = 1e30f, d1 = 1e30f, d2 = 1e30f;
    int   i0 = 0,     i1 = 0,     i2 = 0;
    #pragma unroll
    for (int ck = 0; ck < NCHUNK; ++ck) {
        const float2* pe = part + ((size_t)ck * ROWS2 + row) * 3;
        #pragma unroll
        for (int h = 0; h < 3; ++h) {
            float2 v = pe[h];
            float d = v.x;
            int   i = __float_as_int(v.y);
            if (d < d2) {
                if (d < d1) {
                    d2 = d1; i2 = i1;
                    if (d < d0) { d1 = d0; i1 = i0; d0 = d; i0 = i; }
                    else        { d1 = d;  i1 = i; }
                } else { d2 = d; i2 = i; }
            }
        }
    }
    const float r0 = 1.0f / (d0 + NN_EPS);
    const float r1 = 1.0f / (d1 + NN_EPS);
    const float r2 = 1.0f / (d2 + NN_EPS);
    const float irs = 1.0f / (r0 + r1 + r2);
    const float w0 = r0 * irs, w1 = r1 * irs, w2 = r2 * irs;

    const float4 sum1 = *(const float4*)&stats[c];
    const float4 sq1  = *(const float4*)&stats[COUT + c];
    const float4 sum2 = *(const float4*)&stats[512 + c];
    const float4 sq2  = *(const float4*)&stats[768 + c];
    const float4 gg1  = *(const float4*)&g1[c];
    const float4 bb1  = *(const float4*)&b1[c];
    const float4 gg2  = *(const float4*)&g2[c];
    const float4 bb2  = *(const float4*)&b2[c];

    const float inv1 = 1.0f / (float)ROWS1, inv2 = 1.0f / (float)ROWS2;
    float4 sc1, sh1, sc2, sh2;
    {
        float m, v;
        m = sum1.x*inv1; v = fmaf(-m,m,sq1.x*inv1); sc1.x = gg1.x/sqrtf(v+BN_EPS); sh1.x = fmaf(-m,sc1.x,bb1.x);
        m = sum1.y*inv1; v = fmaf(-m,m,sq1.y*inv1); sc1.y = gg1.y/sqrtf(v+BN_EPS); sh1.y = fmaf(-m,sc1.y,bb1.y);
        m = sum1.z*inv1; v = fmaf(-m,m,sq1.z*inv1); sc1.z = gg1.z/sqrtf(v+BN_EPS); sh1.z = fmaf(-m,sc1.z,bb1.z);
        m = sum1.w*inv1; v = fmaf(-m,m,sq1.w*inv1); sc1.w = gg1.w/sqrtf(v+BN_EPS); sh1.w = fmaf(-m,sc1.w,bb1.w);
        m = sum2.x*inv2; v = fmaf(-m,m,sq2.x*inv2); sc2.x = gg2.x/sqrtf(v+BN_EPS); sh2.x = fmaf(-m,sc2.x,bb2.x);
        m = sum2.y*inv2; v = fmaf(-m,m,sq2.y*inv2); sc2.y = gg2.y/sqrtf(v+BN_EPS); sh2.y = fmaf(-m,sc2.y,bb2.y);
        m = sum2.z*inv2; v = fmaf(-m,m,sq2.z*inv2); sc2.z = gg2.z/sqrtf(v+BN_EPS); sh2.z = fmaf(-m,sc2.z,bb2.z);
        m = sum2.w*inv2; v = fmaf(-m,m,sq2.w*inv2); sc2.w = gg2.w/sqrtf(v+BN_EPS); sh2.w = fmaf(-m,sc2.w,bb2.w);
    }

    const float* hb = h1 + (size_t)b * NPTS * COUT + c;
    const float4 h0 = *(const float4*)(hb + (size_t)i0 * COUT);
    const float4 h4 = *(const float4*)(hb + (size_t)i1 * COUT);
    const float4 h8 = *(const float4*)(hb + (size_t)i2 * COUT);

    const size_t oi = (size_t)row * COUT + c;
    float4 yv = *(const float4*)&out[oi];
    float4 r;
    r.x = fmaxf(fmaf(yv.x, sc2.x, sh2.x), 0.f)
        + w0 * fmaxf(fmaf(h0.x, sc1.x, sh1.x), 0.f)
        + w1 * fmaxf(fmaf(h4.x, sc1.x, sh1.x), 0.f)
        + w2 * fmaxf(fmaf(h8.x, sc1.x, sh1.x), 0.f);
    r.y = fmaxf(fmaf(yv.y, sc2.y, sh2.y), 0.f)
        + w0 * fmaxf(fmaf(h0.y, sc1.y, sh1.y), 0.f)
        + w1 * fmaxf(fmaf(h4.y, sc1.y, sh1.y), 0.f)
        + w2 * fmaxf(fmaf(h8.y, sc1.y, sh1.y), 0.f);
    r.z = fmaxf(fmaf(yv.z, sc2.z, sh2.z), 0.f)
        + w0 * fmaxf(fmaf(h0.z, sc1.z, sh1.z), 0.f)
        + w1 * fmaxf(fmaf(h4.z, sc1.z, sh1.z), 0.f)
        + w2 * fmaxf(fmaf(h8.z, sc1.z, sh1.z), 0.f);
    r.w = fmaxf(fmaf(yv.w, sc2.w, sh2.w), 0.f)
        + w0 * fmaxf(fmaf(h0.w, sc1.w, sh1.w), 0.f)
        + w1 * fmaxf(fmaf(h4.w, sc1.w, sh1.w), 0.f)
        + w2 * fmaxf(fmaf(h8.w, sc1.w, sh1.w), 0.f);
    *(float4*)&out[oi] = r;
}

// ---------------------------------------------------------------------------
extern "C" void kernel_launch(void* const* d_in, const int* in_sizes, int n_in,
                              void* d_out, int out_size, void* d_ws, size_t ws_size,
                              hipStream_t stream) {
    const float* x1       = (const float*)d_in[0];
    const float* p1       = (const float*)d_in[1];
    const float* x2       = (const float*)d_in[2];
    const float* p2       = (const float*)d_in[3];
    const float* W_up     = (const float*)d_in[4];
    const float* gamma_up = (const float*)d_in[5];
    const float* beta_up  = (const float*)d_in[6];
    const float* W_lat    = (const float*)d_in[7];
    const float* gamma_lat= (const float*)d_in[8];
    const float* beta_lat = (const float*)d_in[9];
    float* out = (float*)d_out;

    // workspace layout (~24 MB)
    char* w = (char*)d_ws;
    unsigned short* x1h = (unsigned short*)(w);                           // 4 MB
    unsigned short* x2h = (unsigned short*)(w + (4u<<20));                // 8 MB
    unsigned short* wuh = (unsigned short*)(w + (12u<<20));               // 256 KB
    unsigned short* wlh = (unsigned short*)(w + (12u<<20) + (256u<<10));  // 128 KB
    float*  h1    = (float*)(w + (13u<<20));                              // 4 MB
    float*  stats = (float*)(w + (17u<<20));                              // 4 KB
    float2* part  = (float2*)(w + (17u<<20) + (16u<<10));                 // 6.3 MB

    hipMemsetAsync(stats, 0, 1024 * sizeof(float), stream);

    // K1a: bf16 split (3168 blocks)
    split_pre<<<3168, 256, 0, stream>>>(x1, x2, W_up, W_lat, x1h, x2h, wuh, wlh);

    // K1b: three_nn partials (1024 blocks)
    nn_part<<<dim3(MPTS / 256, NCHUNK, BATCH), 256, 0, stream>>>(p1, p2, part);

    // K2: both GEMMs, 1280 blocks, full-K, fused BN stats
    gemm_fused<<<1280, 256, 0, stream>>>(x1h, wuh, x2h, wlh, h1, out, stats);

    // K3: merge + gather-interp (+BN1+ReLU) + BN2 + ReLU + add
    final_combine<<<ROWS2 / 4, 256, 0, stream>>>(h1, stats, gamma_up, beta_up,
                                                 gamma_lat, beta_lat, part, out);

    // p2 passthrough -> second output
    hipMemcpyAsync(out + (size_t)ROWS2 * COUT, p2,
                   (size_t)ROWS2 * 3 * sizeof(float),
                   hipMemcpyDeviceToDevice, stream);
}